// Round 15
// baseline (931.180 us; speedup 1.0000x reference)
//
#include <hip/hip_runtime.h>

// EntailmentSelfAttention: N=16, L=256, S=2, H=16, D=64, E=1024
//
// Pipeline (5 kernels):
//   K0 k_wot   : one-time column permutation WoT[f][e'] = Wo[f][perm(e')],
//                e' = hr*128 + sp*64 + d, perm(e') = hr*128 + 2d + sp.
//                Removes the per-block parity gather from k_wo (was 2x Wo
//                reads + branch + 4 scalar LDS writes per thread per k0,
//                x512 blocks x32 steps). 4 MB, ~10us.
//   K1 k_proj  : vP/kP/qP[n][h][s][l][d] = row @ W^T (frozen).
//   K2 k_stats : Z_l = sum_q exp(masked S*scale) (pv2-clone shape, frozen).
//   K3 k_pv2   : S recompute + att + PV (r9 shape, frozen, ~310us/17.2GF).
//   K4 k_wo    : out = X' @ WoT^T + bo. 256 thr, acc[8][8] (the 2.0 flop/
//                LDS-byte shape; r14's 4x8 was 1.33), BK=64: barriers
//                64->32, per-barrier compute 2x (pv2-like density), both
//                operands stage as pure contiguous f4 row segments (the
//                64-wide e'-slab has fixed (hr,sp) so X rows are straight
//                256-B reads). r11: 480us @44% VALU; r14 512-thr: 504us
//                @44% VALU, Occ 12->43% no help -> occupancy exonerated,
//                staging overhead + barrier count indicted.
//
// ws layout (f32): vP @0, kP @8388608, qP @16777216, X @25165824,
//                  St(float2) @33554432 (262144 f), WoT @33816576
//                  (1048576 f). Total 139.5 MB.

__global__ __launch_bounds__(256) void k_wot(
    const float* __restrict__ Wo, float* __restrict__ WoT)
{
    const int f = blockIdx.x;          // 0..1023
    const int e4 = threadIdx.x * 4;    // e' base, d%4==0
    const int hr = e4 >> 7, sp = (e4 >> 6) & 1, d = e4 & 63;
    const float* wrow = Wo + (long)f * 1024 + hr * 128 + 2 * d;  // aligned
    float4 pA = *(const float4*)(wrow);
    float4 pB = *(const float4*)(wrow + 4);
    float4 o;
    if (sp == 0) { o.x = pA.x; o.y = pA.z; o.z = pB.x; o.w = pB.z; }
    else         { o.x = pA.y; o.y = pA.w; o.z = pB.y; o.w = pB.w; }
    *(float4*)(WoT + (long)f * 1024 + e4) = o;
}

__global__ __launch_bounds__(256) void k_proj(
    const float* __restrict__ Av, const float* __restrict__ Ak,
    const float* __restrict__ Aq, const float* __restrict__ Wv,
    const float* __restrict__ Wk, const float* __restrict__ Wq,
    float* __restrict__ vP, float* __restrict__ kP, float* __restrict__ qP)
{
    __shared__ float As[3][64][36];
    __shared__ float Ws[3][64][36];
    const int b = blockIdx.x;
    const int h = b & 15, s = (b >> 4) & 1, lblk = (b >> 5) & 3, n = b >> 7;
    const int l0 = lblk * 64;
    const float* Asrc[3] = {Av, Ak, Aq};
    const float* Wsrc[3] = {Wv, Wk, Wq};
    float* Pdst[3] = {vP, kP, qP};
    const int tid = threadIdx.x;
    const int ty = tid >> 4, tx = tid & 15;

    float acc[3][4][4];
#pragma unroll
    for (int m = 0; m < 3; ++m)
#pragma unroll
        for (int i = 0; i < 4; ++i)
#pragma unroll
            for (int j = 0; j < 4; ++j) acc[m][i][j] = 0.f;

    const long baseA = (long)n * 524288 + (long)l0 * 2048 + s * 1024 + h * 64;

#pragma unroll
    for (int k0 = 0; k0 < 64; k0 += 32) {
        __syncthreads();
#pragma unroll
        for (int m = 0; m < 3; ++m) {
#pragma unroll
            for (int w = 0; w < 2; ++w) {
                int idx = w * 1024 + tid * 4;
                int r = idx >> 5, c = idx & 31;
                *(float4*)&As[m][r][c] =
                    *(const float4*)(Asrc[m] + baseA + (long)r * 2048 + k0 + c);
                *(float4*)&Ws[m][r][c] =
                    *(const float4*)(Wsrc[m] + r * 64 + k0 + c);
            }
        }
        __syncthreads();
#pragma unroll
        for (int kk = 0; kk < 32; kk += 4) {
            float4 a[3][4], wb[3][4];
#pragma unroll
            for (int m = 0; m < 3; ++m)
#pragma unroll
                for (int i = 0; i < 4; ++i)
                    a[m][i] = *(const float4*)&As[m][ty + 16 * i][kk];
#pragma unroll
            for (int m = 0; m < 3; ++m)
#pragma unroll
                for (int j = 0; j < 4; ++j)
                    wb[m][j] = *(const float4*)&Ws[m][tx + 16 * j][kk];
#pragma unroll
            for (int m = 0; m < 3; ++m)
#pragma unroll
                for (int i = 0; i < 4; ++i)
#pragma unroll
                    for (int j = 0; j < 4; ++j) {
                        acc[m][i][j] += a[m][i].x * wb[m][j].x;
                        acc[m][i][j] += a[m][i].y * wb[m][j].y;
                        acc[m][i][j] += a[m][i].z * wb[m][j].z;
                        acc[m][i][j] += a[m][i].w * wb[m][j].w;
                    }
        }
    }

    const long pbase = ((long)((n * 16 + h) * 2 + s)) * 16384 + (long)l0 * 64;
#pragma unroll
    for (int m = 0; m < 3; ++m)
#pragma unroll
        for (int i = 0; i < 4; ++i)
#pragma unroll
            for (int j = 0; j < 4; ++j)
                Pdst[m][pbase + (ty + 16 * i) * 64 + tx + 16 * j] = acc[m][i][j];
}

// Stats pass (r11 shape, frozen): block = (nhs, lhalf of 128 l), 512 thr.
__global__ __launch_bounds__(512, 4) void k_stats(
    const float* __restrict__ kP, const float* __restrict__ qP,
    const int* __restrict__ mask, float2* __restrict__ St)
{
    __shared__ float Ks[128][68];    // 34,816 B
    __shared__ float Qs[32][68];     //  8,704 B
    __shared__ float atts[32][132];  // 16,896 B
    const int b = blockIdx.x;
    const int nhs = b >> 1, lblk = b & 1;
    const int n = nhs >> 5, h = (nhs >> 1) & 15, s = nhs & 1;
    const long slice = (long)nhs * 16384;
    const int l0 = lblk * 128;
    const int tid = threadIdx.x;
    const int tyS = tid >> 4, tx = tid & 15;   // tyS 0..31

#pragma unroll
    for (int w = 0; w < 4; ++w) {
        int r = w * 32 + tyS, c = tx * 4;
        *(float4*)&Ks[r][c] = *(const float4*)(kP + slice + (l0 + r) * 64 + c);
    }

    const int mrow = n * 524288 + (h >> 3) * 262144 + (h & 7) * 32 + s * 16;
    const float scale = 0.03125f;  // 1/sqrt(1024)
    float zrun = 0.f;              // threads<128: running Z for l = l0+tid

#pragma unroll 1
    for (int qs = 0; qs < 8; ++qs) {
        __syncthreads();  // Ks ready (qs=0) / prev atts consumed by reduce
        {
            int r = tyS, c = tx * 4;
            *(float4*)&Qs[r][c] =
                *(const float4*)(qP + slice + (qs * 32 + r) * 64 + c);
        }
        __syncthreads();

        const int q = qs * 32 + tyS;
        const float live = (mask[mrow + (q >> 4)] != 0) ? 1.f : 0.f;

#pragma unroll
        for (int jh = 0; jh < 2; ++jh) {
            float satt[4];
#pragma unroll
            for (int jj = 0; jj < 4; ++jj) satt[jj] = 0.f;
#pragma unroll
            for (int kk = 0; kk < 64; kk += 4) {
                float4 a = *(const float4*)&Qs[tyS][kk];
                float4 bk[4];
#pragma unroll
                for (int jj = 0; jj < 4; ++jj)
                    bk[jj] = *(const float4*)&Ks[tx + 16 * (jh * 4 + jj)][kk];
#pragma unroll
                for (int jj = 0; jj < 4; ++jj) {
                    satt[jj] += a.x * bk[jj].x;
                    satt[jj] += a.y * bk[jj].y;
                    satt[jj] += a.z * bk[jj].z;
                    satt[jj] += a.w * bk[jj].w;
                }
            }
#pragma unroll
            for (int jj = 0; jj < 4; ++jj) {
                const int lp = tx + 16 * (jh * 4 + jj);
                atts[tyS][lp] =
                    (live != 0.f) ? expf(satt[jj] * scale) : 0.f;
            }
        }
        __syncthreads();

        if (tid < 128) {
            float zz = 0.f;
#pragma unroll
            for (int r = 0; r < 32; ++r) zz += atts[r][tid];
            zrun += zz;
        }
    }

    if (tid < 128) {
        float2 st = (zrun > 0.f) ? make_float2(0.f, 1.0f / zrun)
                                 : make_float2(-3.125e18f, 1.0f / 256.0f);
        St[nhs * 256 + l0 + tid] = st;
    }
}

// PV pass (r9 shape, frozen): block = (nhs, qblk of 128 q). 512 threads.
__global__ __launch_bounds__(512, 4) void k_pv2(
    const float* __restrict__ kP, const float* __restrict__ qP,
    const float* __restrict__ vP, const int* __restrict__ mask,
    const float2* __restrict__ St, float* __restrict__ X)
{
    __shared__ float Qs[128][68];    // 34,816 B
    __shared__ float Ks[32][68];     //  8,704 B
    __shared__ float vs[32][68];     //  8,704 B
    __shared__ float atts[32][132];  // 16,896 B
    __shared__ float2 sst[32];       //    256 B
    __shared__ int mb8[8];
    const int b = blockIdx.x;
    const int nhs = b >> 1, qblk = b & 1;
    const int n = nhs >> 5, h = (nhs >> 1) & 15, s = nhs & 1;
    const long slice = (long)nhs * 16384;
    const int q0 = qblk * 128;
    const int tid = threadIdx.x;
    const int tyS = tid >> 4, tx = tid & 15;   // tyS 0..31

#pragma unroll
    for (int w = 0; w < 4; ++w) {
        int r = w * 32 + tyS, c = tx * 4;
        *(float4*)&Qs[r][c] =
            *(const float4*)(qP + slice + (q0 + r) * 64 + c);
    }
    const int mrow = n * 524288 + (h >> 3) * 262144 + (h & 7) * 32 + s * 16;
    if (tid < 8) mb8[tid] = mask[mrow + qblk * 8 + tid];

    const int pq = tid & 127, d0 = (tid >> 7) * 16;
    float acc[16];
#pragma unroll
    for (int j = 0; j < 16; ++j) acc[j] = 0.f;

    const float scale = 0.03125f;

#pragma unroll 1
    for (int sl = 0; sl < 8; ++sl) {
        __syncthreads();
        {
            int r = tyS, c = tx * 4;
            *(float4*)&Ks[r][c] =
                *(const float4*)(kP + slice + (sl * 32 + r) * 64 + c);
            *(float4*)&vs[r][c] =
                *(const float4*)(vP + slice + (sl * 32 + r) * 64 + c);
        }
        if (tid < 32) sst[tid] = St[nhs * 256 + sl * 32 + tid];
        __syncthreads();

        const float2 st = sst[tyS];
#pragma unroll
        for (int jh = 0; jh < 2; ++jh) {
            float satt[4];
#pragma unroll
            for (int jj = 0; jj < 4; ++jj) satt[jj] = 0.f;
#pragma unroll
            for (int kk = 0; kk < 64; kk += 4) {
                float4 a = *(const float4*)&Ks[tyS][kk];
                float4 bq[4];
#pragma unroll
                for (int jj = 0; jj < 4; ++jj)
                    bq[jj] = *(const float4*)&Qs[tx + 16 * (jh * 4 + jj)][kk];
#pragma unroll
                for (int jj = 0; jj < 4; ++jj) {
                    satt[jj] += a.x * bq[jj].x;
                    satt[jj] += a.y * bq[jj].y;
                    satt[jj] += a.z * bq[jj].z;
                    satt[jj] += a.w * bq[jj].w;
                }
            }
#pragma unroll
            for (int jj = 0; jj < 4; ++jj) {
                const int j = jh * 4 + jj;
                float sv = (mb8[j] != 0) ? satt[jj] * scale : -3.125e18f;
                atts[tyS][tx + 16 * j] = expf(sv - st.x) * st.y;
            }
        }
        __syncthreads();

#pragma unroll 2
        for (int lc = 0; lc < 32; ++lc) {
            float a0 = atts[lc][pq];
            float4 v0 = *(const float4*)&vs[lc][d0];
            float4 v1 = *(const float4*)&vs[lc][d0 + 4];
            float4 v2 = *(const float4*)&vs[lc][d0 + 8];
            float4 v3 = *(const float4*)&vs[lc][d0 + 12];
            acc[0]  += a0 * v0.x; acc[1]  += a0 * v0.y;
            acc[2]  += a0 * v0.z; acc[3]  += a0 * v0.w;
            acc[4]  += a0 * v1.x; acc[5]  += a0 * v1.y;
            acc[6]  += a0 * v1.z; acc[7]  += a0 * v1.w;
            acc[8]  += a0 * v2.x; acc[9]  += a0 * v2.y;
            acc[10] += a0 * v2.z; acc[11] += a0 * v2.w;
            acc[12] += a0 * v3.x; acc[13] += a0 * v3.y;
            acc[14] += a0 * v3.z; acc[15] += a0 * v3.w;
        }
    }

    {
        long xb = slice + (long)(q0 + pq) * 64 + d0;
#pragma unroll
        for (int k = 0; k < 4; ++k) {
            float4 o = {acc[4 * k], acc[4 * k + 1],
                        acc[4 * k + 2], acc[4 * k + 3]};
            *(float4*)&X[xb + 4 * k] = o;
        }
    }
}

// out[r][f] = sum_e' Xrow[r][e'] WoT[f][e'] + bo[f], r = (n*256+q)*2+s2.
// e' = hr*128+sp*64+d matches X slice layout: slab of 64 e' has fixed
// (hr,sp) -> X staging is a straight 256-B row read. BK=64: 16 k0 steps
// (32 barriers, was 64), per-barrier compute 2x. 256 thr, acc[8][8]
// (2.0 flop/LDS-byte). LDS 69.6 KB -> 2 blocks/CU.
__global__ __launch_bounds__(256) void k_wo(
    const float* __restrict__ X, const float* __restrict__ WoT,
    const float* __restrict__ bo, float* __restrict__ out)
{
    __shared__ float Xs[128][68];
    __shared__ float Ws[128][68];
    const int b = blockIdx.x;
    const int by = b >> 3, bx = b & 7;
    const int r0 = by * 128, f0 = bx * 128;
    const int tid = threadIdx.x, ty = tid >> 4, tx = tid & 15;

    float acc[8][8];
#pragma unroll
    for (int i = 0; i < 8; ++i)
#pragma unroll
        for (int j = 0; j < 8; ++j) acc[i][j] = 0.f;

#pragma unroll 1
    for (int k0 = 0; k0 < 1024; k0 += 64) {
        const int hr = k0 >> 7;         // head-in-group 0..7
        const int sp = (k0 >> 6) & 1;   // s parity
        __syncthreads();
#pragma unroll
        for (int w = 0; w < 8; ++w) {
            int r = w * 16 + ty, c = tx * 4;
            int R = r0 + r;
            int n = R >> 9, q = (R >> 1) & 255, s2 = R & 1;
            long xoff = ((long)((n * 16 + (s2 * 8 + hr)) * 2 + sp)) * 16384 +
                        q * 64 + c;
            *(float4*)&Xs[r][c] = *(const float4*)(X + xoff);
            *(float4*)&Ws[r][c] =
                *(const float4*)(WoT + (long)(f0 + r) * 1024 + k0 + c);
        }
        __syncthreads();
#pragma unroll
        for (int kk = 0; kk < 64; kk += 4) {
            float4 a[8], bb[8];
#pragma unroll
            for (int i = 0; i < 8; ++i)
                a[i] = *(const float4*)&Xs[ty + 16 * i][kk];
#pragma unroll
            for (int j = 0; j < 8; ++j)
                bb[j] = *(const float4*)&Ws[tx + 16 * j][kk];
#pragma unroll
            for (int i = 0; i < 8; ++i)
#pragma unroll
                for (int j = 0; j < 8; ++j) {
                    acc[i][j] += a[i].x * bb[j].x;
                    acc[i][j] += a[i].y * bb[j].y;
                    acc[i][j] += a[i].z * bb[j].z;
                    acc[i][j] += a[i].w * bb[j].w;
                }
        }
    }

#pragma unroll
    for (int i = 0; i < 8; ++i)
#pragma unroll
        for (int j = 0; j < 8; ++j) {
            int r = r0 + ty + 16 * i, f = f0 + tx + 16 * j;
            out[(long)r * 1024 + f] = acc[i][j] + bo[f];
        }
}

extern "C" void kernel_launch(void* const* d_in, const int* in_sizes, int n_in,
                              void* d_out, int out_size, void* d_ws,
                              size_t ws_size, hipStream_t stream)
{
    const float* vals = (const float*)d_in[0];
    const float* keys = (const float*)d_in[1];
    const float* qrys = (const float*)d_in[2];
    const int*   mask = (const int*)d_in[3];
    const float* Wv   = (const float*)d_in[4];
    const float* Wk   = (const float*)d_in[5];
    const float* Wq   = (const float*)d_in[6];
    const float* Wo   = (const float*)d_in[7];
    const float* bo   = (const float*)d_in[8];
    float* ws  = (float*)d_ws;
    float* vP  = ws;
    float* kP  = ws + 8388608;
    float* qP  = ws + 16777216;
    float* X   = ws + 25165824;
    float2* St = (float2*)(ws + 33554432);
    float* WoT = ws + 33816576;
    float* out = (float*)d_out;

    k_wot  <<<1024, 256, 0, stream>>>(Wo, WoT);
    k_proj <<<2048, 256, 0, stream>>>(vals, keys, qrys, Wv, Wk, Wq, vP, kP, qP);
    k_stats<<<1024, 512, 0, stream>>>(kP, qP, mask, St);
    k_pv2  <<<1024, 512, 0, stream>>>(kP, qP, vP, mask, St, X);
    k_wo   <<< 512, 256, 0, stream>>>(X, WoT, bo, out);
}

// Round 16
// 753.719 us; speedup vs baseline: 1.2354x; 1.2354x over previous
//
#include <hip/hip_runtime.h>

// EntailmentSelfAttention: N=16, L=256, S=2, H=16, D=64, E=1024
//
// Pipeline (5 kernels):
//   K0 k_wot   : WoT2[e'][f] = Wo[f][perm(e')], e' = hr*128+sp*64+d,
//                perm = hr*128+2d+sp. TRANSPOSED layout so k_wo can read
//                Ws rows [e][f] as wave-BROADCAST f4s.
//   K1 k_proj  : frozen.
//   K2 k_stats : frozen (r11 pv2-clone shape).
//   K3 k_pv2   : frozen (r9 shape, ~55 TF - session best).
//   K4 k_wo    : broadcast-GEMM, exact pv2-PV clone. Insight from r15:
//                spread ds_read_b128 (~12cyc, per-lane rows) starve FMA;
//                pv2's PV loop wins because V reads are wave-broadcast
//                (d0 wave-uniform -> one 16B fetch serves 64 lanes).
//                Thread owns 1 out-row (pq, spread scalar) x 32 f
//                (fg wave-uniform -> all Ws reads broadcast). 32 e-slabs:
//                stage XsT[32][132] transposed (stride 132: spread scalar
//                reads (4e+pq)%32 -> 2-way free) + Ws[32][132] straight f4.
//                33.8KB LDS -> 4 blocks/CU, acc[32], ~90 VGPR.
//                r11: 480us; r14: 504; r15: 537. FMA floor ~110us.
//
// ws layout (f32): vP @0, kP @8388608, qP @16777216, X @25165824,
//                  St(float2) @33554432 (262144 f), WoT2 @33816576
//                  (1048576 f). Total 139.5 MB.

__global__ __launch_bounds__(256) void k_wot(
    const float* __restrict__ Wo, float* __restrict__ WoT2)
{
    const int f = blockIdx.x;          // 0..1023
    const int e4 = threadIdx.x * 4;    // e' base (d%4==0, same hr/sp)
    const int hr = e4 >> 7, sp = (e4 >> 6) & 1, d = e4 & 63;
    const float* wrow = Wo + (long)f * 1024 + hr * 128 + 2 * d + sp;
    float v0 = wrow[0], v1 = wrow[2], v2 = wrow[4], v3 = wrow[6];
    WoT2[(long)(e4 + 0) * 1024 + f] = v0;
    WoT2[(long)(e4 + 1) * 1024 + f] = v1;
    WoT2[(long)(e4 + 2) * 1024 + f] = v2;
    WoT2[(long)(e4 + 3) * 1024 + f] = v3;
}

__global__ __launch_bounds__(256) void k_proj(
    const float* __restrict__ Av, const float* __restrict__ Ak,
    const float* __restrict__ Aq, const float* __restrict__ Wv,
    const float* __restrict__ Wk, const float* __restrict__ Wq,
    float* __restrict__ vP, float* __restrict__ kP, float* __restrict__ qP)
{
    __shared__ float As[3][64][36];
    __shared__ float Ws[3][64][36];
    const int b = blockIdx.x;
    const int h = b & 15, s = (b >> 4) & 1, lblk = (b >> 5) & 3, n = b >> 7;
    const int l0 = lblk * 64;
    const float* Asrc[3] = {Av, Ak, Aq};
    const float* Wsrc[3] = {Wv, Wk, Wq};
    float* Pdst[3] = {vP, kP, qP};
    const int tid = threadIdx.x;
    const int ty = tid >> 4, tx = tid & 15;

    float acc[3][4][4];
#pragma unroll
    for (int m = 0; m < 3; ++m)
#pragma unroll
        for (int i = 0; i < 4; ++i)
#pragma unroll
            for (int j = 0; j < 4; ++j) acc[m][i][j] = 0.f;

    const long baseA = (long)n * 524288 + (long)l0 * 2048 + s * 1024 + h * 64;

#pragma unroll
    for (int k0 = 0; k0 < 64; k0 += 32) {
        __syncthreads();
#pragma unroll
        for (int m = 0; m < 3; ++m) {
#pragma unroll
            for (int w = 0; w < 2; ++w) {
                int idx = w * 1024 + tid * 4;
                int r = idx >> 5, c = idx & 31;
                *(float4*)&As[m][r][c] =
                    *(const float4*)(Asrc[m] + baseA + (long)r * 2048 + k0 + c);
                *(float4*)&Ws[m][r][c] =
                    *(const float4*)(Wsrc[m] + r * 64 + k0 + c);
            }
        }
        __syncthreads();
#pragma unroll
        for (int kk = 0; kk < 32; kk += 4) {
            float4 a[3][4], wb[3][4];
#pragma unroll
            for (int m = 0; m < 3; ++m)
#pragma unroll
                for (int i = 0; i < 4; ++i)
                    a[m][i] = *(const float4*)&As[m][ty + 16 * i][kk];
#pragma unroll
            for (int m = 0; m < 3; ++m)
#pragma unroll
                for (int j = 0; j < 4; ++j)
                    wb[m][j] = *(const float4*)&Ws[m][tx + 16 * j][kk];
#pragma unroll
            for (int m = 0; m < 3; ++m)
#pragma unroll
                for (int i = 0; i < 4; ++i)
#pragma unroll
                    for (int j = 0; j < 4; ++j) {
                        acc[m][i][j] += a[m][i].x * wb[m][j].x;
                        acc[m][i][j] += a[m][i].y * wb[m][j].y;
                        acc[m][i][j] += a[m][i].z * wb[m][j].z;
                        acc[m][i][j] += a[m][i].w * wb[m][j].w;
                    }
        }
    }

    const long pbase = ((long)((n * 16 + h) * 2 + s)) * 16384 + (long)l0 * 64;
#pragma unroll
    for (int m = 0; m < 3; ++m)
#pragma unroll
        for (int i = 0; i < 4; ++i)
#pragma unroll
            for (int j = 0; j < 4; ++j)
                Pdst[m][pbase + (ty + 16 * i) * 64 + tx + 16 * j] = acc[m][i][j];
}

// Stats pass (frozen): block = (nhs, lhalf of 128 l), 512 thr.
__global__ __launch_bounds__(512, 4) void k_stats(
    const float* __restrict__ kP, const float* __restrict__ qP,
    const int* __restrict__ mask, float2* __restrict__ St)
{
    __shared__ float Ks[128][68];    // 34,816 B
    __shared__ float Qs[32][68];     //  8,704 B
    __shared__ float atts[32][132];  // 16,896 B
    const int b = blockIdx.x;
    const int nhs = b >> 1, lblk = b & 1;
    const int n = nhs >> 5, h = (nhs >> 1) & 15, s = nhs & 1;
    const long slice = (long)nhs * 16384;
    const int l0 = lblk * 128;
    const int tid = threadIdx.x;
    const int tyS = tid >> 4, tx = tid & 15;   // tyS 0..31

#pragma unroll
    for (int w = 0; w < 4; ++w) {
        int r = w * 32 + tyS, c = tx * 4;
        *(float4*)&Ks[r][c] = *(const float4*)(kP + slice + (l0 + r) * 64 + c);
    }

    const int mrow = n * 524288 + (h >> 3) * 262144 + (h & 7) * 32 + s * 16;
    const float scale = 0.03125f;  // 1/sqrt(1024)
    float zrun = 0.f;              // threads<128: running Z for l = l0+tid

#pragma unroll 1
    for (int qs = 0; qs < 8; ++qs) {
        __syncthreads();  // Ks ready (qs=0) / prev atts consumed by reduce
        {
            int r = tyS, c = tx * 4;
            *(float4*)&Qs[r][c] =
                *(const float4*)(qP + slice + (qs * 32 + r) * 64 + c);
        }
        __syncthreads();

        const int q = qs * 32 + tyS;
        const float live = (mask[mrow + (q >> 4)] != 0) ? 1.f : 0.f;

#pragma unroll
        for (int jh = 0; jh < 2; ++jh) {
            float satt[4];
#pragma unroll
            for (int jj = 0; jj < 4; ++jj) satt[jj] = 0.f;
#pragma unroll
            for (int kk = 0; kk < 64; kk += 4) {
                float4 a = *(const float4*)&Qs[tyS][kk];
                float4 bk[4];
#pragma unroll
                for (int jj = 0; jj < 4; ++jj)
                    bk[jj] = *(const float4*)&Ks[tx + 16 * (jh * 4 + jj)][kk];
#pragma unroll
                for (int jj = 0; jj < 4; ++jj) {
                    satt[jj] += a.x * bk[jj].x;
                    satt[jj] += a.y * bk[jj].y;
                    satt[jj] += a.z * bk[jj].z;
                    satt[jj] += a.w * bk[jj].w;
                }
            }
#pragma unroll
            for (int jj = 0; jj < 4; ++jj) {
                const int lp = tx + 16 * (jh * 4 + jj);
                atts[tyS][lp] =
                    (live != 0.f) ? expf(satt[jj] * scale) : 0.f;
            }
        }
        __syncthreads();

        if (tid < 128) {
            float zz = 0.f;
#pragma unroll
            for (int r = 0; r < 32; ++r) zz += atts[r][tid];
            zrun += zz;
        }
    }

    if (tid < 128) {
        float2 st = (zrun > 0.f) ? make_float2(0.f, 1.0f / zrun)
                                 : make_float2(-3.125e18f, 1.0f / 256.0f);
        St[nhs * 256 + l0 + tid] = st;
    }
}

// PV pass (frozen): block = (nhs, qblk of 128 q). 512 threads.
__global__ __launch_bounds__(512, 4) void k_pv2(
    const float* __restrict__ kP, const float* __restrict__ qP,
    const float* __restrict__ vP, const int* __restrict__ mask,
    const float2* __restrict__ St, float* __restrict__ X)
{
    __shared__ float Qs[128][68];    // 34,816 B
    __shared__ float Ks[32][68];     //  8,704 B
    __shared__ float vs[32][68];     //  8,704 B
    __shared__ float atts[32][132];  // 16,896 B
    __shared__ float2 sst[32];       //    256 B
    __shared__ int mb8[8];
    const int b = blockIdx.x;
    const int nhs = b >> 1, qblk = b & 1;
    const int n = nhs >> 5, h = (nhs >> 1) & 15, s = nhs & 1;
    const long slice = (long)nhs * 16384;
    const int q0 = qblk * 128;
    const int tid = threadIdx.x;
    const int tyS = tid >> 4, tx = tid & 15;   // tyS 0..31

#pragma unroll
    for (int w = 0; w < 4; ++w) {
        int r = w * 32 + tyS, c = tx * 4;
        *(float4*)&Qs[r][c] =
            *(const float4*)(qP + slice + (q0 + r) * 64 + c);
    }
    const int mrow = n * 524288 + (h >> 3) * 262144 + (h & 7) * 32 + s * 16;
    if (tid < 8) mb8[tid] = mask[mrow + qblk * 8 + tid];

    const int pq = tid & 127, d0 = (tid >> 7) * 16;
    float acc[16];
#pragma unroll
    for (int j = 0; j < 16; ++j) acc[j] = 0.f;

    const float scale = 0.03125f;

#pragma unroll 1
    for (int sl = 0; sl < 8; ++sl) {
        __syncthreads();
        {
            int r = tyS, c = tx * 4;
            *(float4*)&Ks[r][c] =
                *(const float4*)(kP + slice + (sl * 32 + r) * 64 + c);
            *(float4*)&vs[r][c] =
                *(const float4*)(vP + slice + (sl * 32 + r) * 64 + c);
        }
        if (tid < 32) sst[tid] = St[nhs * 256 + sl * 32 + tid];
        __syncthreads();

        const float2 st = sst[tyS];
#pragma unroll
        for (int jh = 0; jh < 2; ++jh) {
            float satt[4];
#pragma unroll
            for (int jj = 0; jj < 4; ++jj) satt[jj] = 0.f;
#pragma unroll
            for (int kk = 0; kk < 64; kk += 4) {
                float4 a = *(const float4*)&Ks[tyS][kk];
                float4 bq[4];
#pragma unroll
                for (int jj = 0; jj < 4; ++jj)
                    bq[jj] = *(const float4*)&Qs[tx + 16 * (jh * 4 + jj)][kk];
#pragma unroll
                for (int jj = 0; jj < 4; ++jj) {
                    satt[jj] += a.x * bq[jj].x;
                    satt[jj] += a.y * bq[jj].y;
                    satt[jj] += a.z * bq[jj].z;
                    satt[jj] += a.w * bq[jj].w;
                }
            }
#pragma unroll
            for (int jj = 0; jj < 4; ++jj) {
                const int j = jh * 4 + jj;
                float sv = (mb8[j] != 0) ? satt[jj] * scale : -3.125e18f;
                atts[tyS][tx + 16 * j] = expf(sv - st.x) * st.y;
            }
        }
        __syncthreads();

#pragma unroll 2
        for (int lc = 0; lc < 32; ++lc) {
            float a0 = atts[lc][pq];
            float4 v0 = *(const float4*)&vs[lc][d0];
            float4 v1 = *(const float4*)&vs[lc][d0 + 4];
            float4 v2 = *(const float4*)&vs[lc][d0 + 8];
            float4 v3 = *(const float4*)&vs[lc][d0 + 12];
            acc[0]  += a0 * v0.x; acc[1]  += a0 * v0.y;
            acc[2]  += a0 * v0.z; acc[3]  += a0 * v0.w;
            acc[4]  += a0 * v1.x; acc[5]  += a0 * v1.y;
            acc[6]  += a0 * v1.z; acc[7]  += a0 * v1.w;
            acc[8]  += a0 * v2.x; acc[9]  += a0 * v2.y;
            acc[10] += a0 * v2.z; acc[11] += a0 * v2.w;
            acc[12] += a0 * v3.x; acc[13] += a0 * v3.y;
            acc[14] += a0 * v3.z; acc[15] += a0 * v3.w;
        }
    }

    {
        long xb = slice + (long)(q0 + pq) * 64 + d0;
#pragma unroll
        for (int k = 0; k < 4; ++k) {
            float4 o = {acc[4 * k], acc[4 * k + 1],
                        acc[4 * k + 2], acc[4 * k + 3]};
            *(float4*)&X[xb + 4 * k] = o;
        }
    }
}

// Broadcast-GEMM k_wo: out[R][f] = sum_e' X'[R][e'] WoT2[e'][f] + bo[f].
// Block = 128 rows x 128 f; 512 thr; thread = row pq x 32 f (fg = tid>>7,
// wave-uniform -> Ws reads broadcast). 32 e-slabs of 32:
//   XsT[e][row] transposed, stride 132 (spread scalar read (4e+pq)%32 ->
//   2-way free); Ws[e][f] straight f4 rows from WoT2.
// LDS 33.8KB -> 4 blocks/CU; acc[32].
__global__ __launch_bounds__(512, 4) void k_wo(
    const float* __restrict__ X, const float* __restrict__ WoT2,
    const float* __restrict__ bo, float* __restrict__ out)
{
    __shared__ float XsT[32][132];   // 16,896 B  [e][row]
    __shared__ float Ws[32][132];    // 16,896 B  [e][f]
    const int b = blockIdx.x;
    const int by = b >> 3, bx = b & 7;
    const int r0 = by * 128, f0 = bx * 128;
    const int tid = threadIdx.x;
    const int pq = tid & 127;        // out row within tile
    const int fb = (tid >> 7) * 32;  // f base within 128 (wave-uniform)

    float acc[32];
#pragma unroll
    for (int j = 0; j < 32; ++j) acc[j] = 0.f;

#pragma unroll 1
    for (int sl = 0; sl < 32; ++sl) {
        const int hr = sl >> 2, sp = (sl >> 1) & 1, dblk = (sl & 1) * 32;
        __syncthreads();
        // stage XsT: 1024 f4 reads -> transposed scalar writes
#pragma unroll
        for (int w = 0; w < 2; ++w) {
            int idx = w * 512 + tid;
            int r = idx >> 3, c4 = (idx & 7) * 4;
            int R = r0 + r;
            int n = R >> 9, q = (R >> 1) & 255, s2 = R & 1;
            long xoff = ((long)((n * 16 + (s2 * 8 + hr)) * 2 + sp)) * 16384 +
                        q * 64 + dblk + c4;
            float4 v = *(const float4*)(X + xoff);
            XsT[c4 + 0][r] = v.x;
            XsT[c4 + 1][r] = v.y;
            XsT[c4 + 2][r] = v.z;
            XsT[c4 + 3][r] = v.w;
        }
        // stage Ws: straight f4 rows
#pragma unroll
        for (int w = 0; w < 2; ++w) {
            int idx = w * 512 + tid;
            int e = idx >> 5, c = (idx & 31) * 4;
            *(float4*)&Ws[e][c] =
                *(const float4*)(WoT2 + (long)(sl * 32 + e) * 1024 + f0 + c);
        }
        __syncthreads();

        // inner: 1 spread scalar + 8 broadcast f4 + 32 FMA per e
#pragma unroll 4
        for (int e = 0; e < 32; ++e) {
            float xv = XsT[e][pq];
            float4 w0 = *(const float4*)&Ws[e][fb + 0];
            float4 w1 = *(const float4*)&Ws[e][fb + 4];
            float4 w2 = *(const float4*)&Ws[e][fb + 8];
            float4 w3 = *(const float4*)&Ws[e][fb + 12];
            float4 w4 = *(const float4*)&Ws[e][fb + 16];
            float4 w5 = *(const float4*)&Ws[e][fb + 20];
            float4 w6 = *(const float4*)&Ws[e][fb + 24];
            float4 w7 = *(const float4*)&Ws[e][fb + 28];
            acc[0]  += xv * w0.x; acc[1]  += xv * w0.y;
            acc[2]  += xv * w0.z; acc[3]  += xv * w0.w;
            acc[4]  += xv * w1.x; acc[5]  += xv * w1.y;
            acc[6]  += xv * w1.z; acc[7]  += xv * w1.w;
            acc[8]  += xv * w2.x; acc[9]  += xv * w2.y;
            acc[10] += xv * w2.z; acc[11] += xv * w2.w;
            acc[12] += xv * w3.x; acc[13] += xv * w3.y;
            acc[14] += xv * w3.z; acc[15] += xv * w3.w;
            acc[16] += xv * w4.x; acc[17] += xv * w4.y;
            acc[18] += xv * w4.z; acc[19] += xv * w4.w;
            acc[20] += xv * w5.x; acc[21] += xv * w5.y;
            acc[22] += xv * w5.z; acc[23] += xv * w5.w;
            acc[24] += xv * w6.x; acc[25] += xv * w6.y;
            acc[26] += xv * w6.z; acc[27] += xv * w6.w;
            acc[28] += xv * w7.x; acc[29] += xv * w7.y;
            acc[30] += xv * w7.z; acc[31] += xv * w7.w;
        }
    }

    // epilogue: out row r0+pq, f = f0+fb+0..31, + bias
    {
        const long ob = (long)(r0 + pq) * 1024 + f0 + fb;
#pragma unroll
        for (int k = 0; k < 8; ++k) {
            float4 bb = *(const float4*)(bo + f0 + fb + 4 * k);
            float4 o = {acc[4 * k] + bb.x, acc[4 * k + 1] + bb.y,
                        acc[4 * k + 2] + bb.z, acc[4 * k + 3] + bb.w};
            *(float4*)(out + ob + 4 * k) = o;
        }
    }
}

extern "C" void kernel_launch(void* const* d_in, const int* in_sizes, int n_in,
                              void* d_out, int out_size, void* d_ws,
                              size_t ws_size, hipStream_t stream)
{
    const float* vals = (const float*)d_in[0];
    const float* keys = (const float*)d_in[1];
    const float* qrys = (const float*)d_in[2];
    const int*   mask = (const int*)d_in[3];
    const float* Wv   = (const float*)d_in[4];
    const float* Wk   = (const float*)d_in[5];
    const float* Wq   = (const float*)d_in[6];
    const float* Wo   = (const float*)d_in[7];
    const float* bo   = (const float*)d_in[8];
    float* ws  = (float*)d_ws;
    float* vP  = ws;
    float* kP  = ws + 8388608;
    float* qP  = ws + 16777216;
    float* X   = ws + 25165824;
    float2* St = (float2*)(ws + 33554432);
    float* WoT2 = ws + 33816576;
    float* out = (float*)d_out;

    k_wot  <<<1024, 256, 0, stream>>>(Wo, WoT2);
    k_proj <<<2048, 256, 0, stream>>>(vals, keys, qrys, Wv, Wk, Wq, vP, kP, qP);
    k_stats<<<1024, 512, 0, stream>>>(kP, qP, mask, St);
    k_pv2  <<<1024, 512, 0, stream>>>(kP, qP, vP, mask, St, X);
    k_wo   <<< 512, 512, 0, stream>>>(X, WoT2, bo, out);
}

// Round 17
// 477.138 us; speedup vs baseline: 1.9516x; 1.5797x over previous
//
#include <hip/hip_runtime.h>

// EntailmentSelfAttention: N=16, L=256, S=2, H=16, D=64, E=1024
//
// Pipeline (5 kernels):
//   K0 k_wot   : Wb[f][e'] = bf16(Wo[f][perm(e')]), e' = hr*128+sp*64+d,
//                perm = hr*128+2d+sp. bf16, f-major (A/B-frag friendly).
//   K1 k_proj  : frozen.
//   K2 k_stats : frozen (r11 pv2-clone shape).
//   K3 k_pv2   : frozen except epilogue writes X as bf16 (only k_wo reads X).
//   K4 k_wo    : bf16 MFMA GEMM (v_mfma_f32_16x16x32_bf16).
//                r16 showed the f32 SIMT ceiling: 8 bcast b128 + 1 scalar
//                ~102 LDS cyc per 64 FMA cyc -> VALUBusy 38%, 348us.
//                MFMA: 16384 flop / ~5cyc instr = 64x flop density on the
//                same LDS diet. Layouts (m89-verified C/D): D col=lane&15,
//                row=(lane>>4)*4+reg; A row=lane&15, k=(lane>>4)*8+j;
//                B col=lane&15, k=(lane>>4)*8+j.
//                Block 128x128, 8 waves (2 row x 4 col), K-chunk 64 = one
//                (hr,sp) d-range -> X staging is straight 128B rows.
//                LDS 2x[128][72]bf16 = 36.9KB (pad 8: 16B-aligned frags,
//                ~2-way banks). Accum f32 in-MFMA; bias in epilogue.
//                Accuracy: bf16-RTN inputs add ~e-4; threshold 4.27e-3,
//                current 9.8e-4 -> headroom.
//
// ws layout (f32 elems): vP @0, kP @8388608, qP @16777216,
//   Xb(bf16, 8.4M ushorts = 16.8MB) @25165824, St(float2) @33554432,
//   Wb(bf16, 1M ushorts) @33816576.

typedef __attribute__((ext_vector_type(8))) short bf16x8;
typedef __attribute__((ext_vector_type(4))) float f32x4;

__device__ inline ushort f2bf(float x) {
    uint u = __float_as_uint(x);
    u += 0x7FFFu + ((u >> 16) & 1u);
    return (ushort)(u >> 16);
}

__global__ __launch_bounds__(256) void k_wot(
    const float* __restrict__ Wo, ushort* __restrict__ Wb)
{
    const int f = blockIdx.x;          // 0..1023
    const int e4 = threadIdx.x * 4;    // e' base (d%4==0, fixed hr/sp)
    const int hr = e4 >> 7, sp = (e4 >> 6) & 1, d = e4 & 63;
    const float* wrow = Wo + (long)f * 1024 + hr * 128 + 2 * d + sp;
    ushort o[4] = {f2bf(wrow[0]), f2bf(wrow[2]), f2bf(wrow[4]), f2bf(wrow[6])};
    *(uint2*)(Wb + (long)f * 1024 + e4) = *(uint2*)o;
}

__global__ __launch_bounds__(256) void k_proj(
    const float* __restrict__ Av, const float* __restrict__ Ak,
    const float* __restrict__ Aq, const float* __restrict__ Wv,
    const float* __restrict__ Wk, const float* __restrict__ Wq,
    float* __restrict__ vP, float* __restrict__ kP, float* __restrict__ qP)
{
    __shared__ float As[3][64][36];
    __shared__ float Ws[3][64][36];
    const int b = blockIdx.x;
    const int h = b & 15, s = (b >> 4) & 1, lblk = (b >> 5) & 3, n = b >> 7;
    const int l0 = lblk * 64;
    const float* Asrc[3] = {Av, Ak, Aq};
    const float* Wsrc[3] = {Wv, Wk, Wq};
    float* Pdst[3] = {vP, kP, qP};
    const int tid = threadIdx.x;
    const int ty = tid >> 4, tx = tid & 15;

    float acc[3][4][4];
#pragma unroll
    for (int m = 0; m < 3; ++m)
#pragma unroll
        for (int i = 0; i < 4; ++i)
#pragma unroll
            for (int j = 0; j < 4; ++j) acc[m][i][j] = 0.f;

    const long baseA = (long)n * 524288 + (long)l0 * 2048 + s * 1024 + h * 64;

#pragma unroll
    for (int k0 = 0; k0 < 64; k0 += 32) {
        __syncthreads();
#pragma unroll
        for (int m = 0; m < 3; ++m) {
#pragma unroll
            for (int w = 0; w < 2; ++w) {
                int idx = w * 1024 + tid * 4;
                int r = idx >> 5, c = idx & 31;
                *(float4*)&As[m][r][c] =
                    *(const float4*)(Asrc[m] + baseA + (long)r * 2048 + k0 + c);
                *(float4*)&Ws[m][r][c] =
                    *(const float4*)(Wsrc[m] + r * 64 + k0 + c);
            }
        }
        __syncthreads();
#pragma unroll
        for (int kk = 0; kk < 32; kk += 4) {
            float4 a[3][4], wb[3][4];
#pragma unroll
            for (int m = 0; m < 3; ++m)
#pragma unroll
                for (int i = 0; i < 4; ++i)
                    a[m][i] = *(const float4*)&As[m][ty + 16 * i][kk];
#pragma unroll
            for (int m = 0; m < 3; ++m)
#pragma unroll
                for (int j = 0; j < 4; ++j)
                    wb[m][j] = *(const float4*)&Ws[m][tx + 16 * j][kk];
#pragma unroll
            for (int m = 0; m < 3; ++m)
#pragma unroll
                for (int i = 0; i < 4; ++i)
#pragma unroll
                    for (int j = 0; j < 4; ++j) {
                        acc[m][i][j] += a[m][i].x * wb[m][j].x;
                        acc[m][i][j] += a[m][i].y * wb[m][j].y;
                        acc[m][i][j] += a[m][i].z * wb[m][j].z;
                        acc[m][i][j] += a[m][i].w * wb[m][j].w;
                    }
        }
    }

    const long pbase = ((long)((n * 16 + h) * 2 + s)) * 16384 + (long)l0 * 64;
#pragma unroll
    for (int m = 0; m < 3; ++m)
#pragma unroll
        for (int i = 0; i < 4; ++i)
#pragma unroll
            for (int j = 0; j < 4; ++j)
                Pdst[m][pbase + (ty + 16 * i) * 64 + tx + 16 * j] = acc[m][i][j];
}

// Stats pass (frozen): block = (nhs, lhalf of 128 l), 512 thr.
__global__ __launch_bounds__(512, 4) void k_stats(
    const float* __restrict__ kP, const float* __restrict__ qP,
    const int* __restrict__ mask, float2* __restrict__ St)
{
    __shared__ float Ks[128][68];    // 34,816 B
    __shared__ float Qs[32][68];     //  8,704 B
    __shared__ float atts[32][132];  // 16,896 B
    const int b = blockIdx.x;
    const int nhs = b >> 1, lblk = b & 1;
    const int n = nhs >> 5, h = (nhs >> 1) & 15, s = nhs & 1;
    const long slice = (long)nhs * 16384;
    const int l0 = lblk * 128;
    const int tid = threadIdx.x;
    const int tyS = tid >> 4, tx = tid & 15;   // tyS 0..31

#pragma unroll
    for (int w = 0; w < 4; ++w) {
        int r = w * 32 + tyS, c = tx * 4;
        *(float4*)&Ks[r][c] = *(const float4*)(kP + slice + (l0 + r) * 64 + c);
    }

    const int mrow = n * 524288 + (h >> 3) * 262144 + (h & 7) * 32 + s * 16;
    const float scale = 0.03125f;  // 1/sqrt(1024)
    float zrun = 0.f;              // threads<128: running Z for l = l0+tid

#pragma unroll 1
    for (int qs = 0; qs < 8; ++qs) {
        __syncthreads();  // Ks ready (qs=0) / prev atts consumed by reduce
        {
            int r = tyS, c = tx * 4;
            *(float4*)&Qs[r][c] =
                *(const float4*)(qP + slice + (qs * 32 + r) * 64 + c);
        }
        __syncthreads();

        const int q = qs * 32 + tyS;
        const float live = (mask[mrow + (q >> 4)] != 0) ? 1.f : 0.f;

#pragma unroll
        for (int jh = 0; jh < 2; ++jh) {
            float satt[4];
#pragma unroll
            for (int jj = 0; jj < 4; ++jj) satt[jj] = 0.f;
#pragma unroll
            for (int kk = 0; kk < 64; kk += 4) {
                float4 a = *(const float4*)&Qs[tyS][kk];
                float4 bk[4];
#pragma unroll
                for (int jj = 0; jj < 4; ++jj)
                    bk[jj] = *(const float4*)&Ks[tx + 16 * (jh * 4 + jj)][kk];
#pragma unroll
                for (int jj = 0; jj < 4; ++jj) {
                    satt[jj] += a.x * bk[jj].x;
                    satt[jj] += a.y * bk[jj].y;
                    satt[jj] += a.z * bk[jj].z;
                    satt[jj] += a.w * bk[jj].w;
                }
            }
#pragma unroll
            for (int jj = 0; jj < 4; ++jj) {
                const int lp = tx + 16 * (jh * 4 + jj);
                atts[tyS][lp] =
                    (live != 0.f) ? expf(satt[jj] * scale) : 0.f;
            }
        }
        __syncthreads();

        if (tid < 128) {
            float zz = 0.f;
#pragma unroll
            for (int r = 0; r < 32; ++r) zz += atts[r][tid];
            zrun += zz;
        }
    }

    if (tid < 128) {
        float2 st = (zrun > 0.f) ? make_float2(0.f, 1.0f / zrun)
                                 : make_float2(-3.125e18f, 1.0f / 256.0f);
        St[nhs * 256 + l0 + tid] = st;
    }
}

// PV pass (r9 shape; epilogue now writes bf16 Xb): 512 threads.
__global__ __launch_bounds__(512, 4) void k_pv2(
    const float* __restrict__ kP, const float* __restrict__ qP,
    const float* __restrict__ vP, const int* __restrict__ mask,
    const float2* __restrict__ St, ushort* __restrict__ Xb)
{
    __shared__ float Qs[128][68];    // 34,816 B
    __shared__ float Ks[32][68];     //  8,704 B
    __shared__ float vs[32][68];     //  8,704 B
    __shared__ float atts[32][132];  // 16,896 B
    __shared__ float2 sst[32];       //    256 B
    __shared__ int mb8[8];
    const int b = blockIdx.x;
    const int nhs = b >> 1, qblk = b & 1;
    const int n = nhs >> 5, h = (nhs >> 1) & 15, s = nhs & 1;
    const long slice = (long)nhs * 16384;
    const int q0 = qblk * 128;
    const int tid = threadIdx.x;
    const int tyS = tid >> 4, tx = tid & 15;   // tyS 0..31

#pragma unroll
    for (int w = 0; w < 4; ++w) {
        int r = w * 32 + tyS, c = tx * 4;
        *(float4*)&Qs[r][c] =
            *(const float4*)(qP + slice + (q0 + r) * 64 + c);
    }
    const int mrow = n * 524288 + (h >> 3) * 262144 + (h & 7) * 32 + s * 16;
    if (tid < 8) mb8[tid] = mask[mrow + qblk * 8 + tid];

    const int pq = tid & 127, d0 = (tid >> 7) * 16;
    float acc[16];
#pragma unroll
    for (int j = 0; j < 16; ++j) acc[j] = 0.f;

    const float scale = 0.03125f;

#pragma unroll 1
    for (int sl = 0; sl < 8; ++sl) {
        __syncthreads();
        {
            int r = tyS, c = tx * 4;
            *(float4*)&Ks[r][c] =
                *(const float4*)(kP + slice + (sl * 32 + r) * 64 + c);
            *(float4*)&vs[r][c] =
                *(const float4*)(vP + slice + (sl * 32 + r) * 64 + c);
        }
        if (tid < 32) sst[tid] = St[nhs * 256 + sl * 32 + tid];
        __syncthreads();

        const float2 st = sst[tyS];
#pragma unroll
        for (int jh = 0; jh < 2; ++jh) {
            float satt[4];
#pragma unroll
            for (int jj = 0; jj < 4; ++jj) satt[jj] = 0.f;
#pragma unroll
            for (int kk = 0; kk < 64; kk += 4) {
                float4 a = *(const float4*)&Ks[tyS][kk];
                float4 bq[4];
#pragma unroll
                for (int jj = 0; jj < 4; ++jj)
                    bq[jj] = *(const float4*)&Qs[tx + 16 * (jh * 4 + jj)][kk];
#pragma unroll
                for (int jj = 0; jj < 4; ++jj) {
                    satt[jj] += a.x * bq[jj].x;
                    satt[jj] += a.y * bq[jj].y;
                    satt[jj] += a.z * bq[jj].z;
                    satt[jj] += a.w * bq[jj].w;
                }
            }
#pragma unroll
            for (int jj = 0; jj < 4; ++jj) {
                const int j = jh * 4 + jj;
                float sv = (mb8[j] != 0) ? satt[jj] * scale : -3.125e18f;
                atts[tyS][tx + 16 * j] = expf(sv - st.x) * st.y;
            }
        }
        __syncthreads();

#pragma unroll 2
        for (int lc = 0; lc < 32; ++lc) {
            float a0 = atts[lc][pq];
            float4 v0 = *(const float4*)&vs[lc][d0];
            float4 v1 = *(const float4*)&vs[lc][d0 + 4];
            float4 v2 = *(const float4*)&vs[lc][d0 + 8];
            float4 v3 = *(const float4*)&vs[lc][d0 + 12];
            acc[0]  += a0 * v0.x; acc[1]  += a0 * v0.y;
            acc[2]  += a0 * v0.z; acc[3]  += a0 * v0.w;
            acc[4]  += a0 * v1.x; acc[5]  += a0 * v1.y;
            acc[6]  += a0 * v1.z; acc[7]  += a0 * v1.w;
            acc[8]  += a0 * v2.x; acc[9]  += a0 * v2.y;
            acc[10] += a0 * v2.z; acc[11] += a0 * v2.w;
            acc[12] += a0 * v3.x; acc[13] += a0 * v3.y;
            acc[14] += a0 * v3.z; acc[15] += a0 * v3.w;
        }
    }

    // write Xb[nhs][q0+pq][d0..d0+15] as bf16 (two 16B stores)
    {
        long xb = slice + (long)(q0 + pq) * 64 + d0;
        ushort tmp[16];
#pragma unroll
        for (int k2 = 0; k2 < 16; ++k2) tmp[k2] = f2bf(acc[k2]);
        *(uint4*)(Xb + xb) = *(uint4*)&tmp[0];
        *(uint4*)(Xb + xb + 8) = *(uint4*)&tmp[8];
    }
}

// MFMA k_wo: out[R][f] = sum_e' X'[R][e'] Wb[f][e'] + bo[f].
// Block 128 rows x 128 f, 512 thr = 8 waves (wr 0..1 x wc 0..3); wave =
// 64 rows x 32 f = 4x2 tiles of 16x16. K-chunk 64 = one (hr,sp) d-range.
__global__ __launch_bounds__(512) void k_wo(
    const ushort* __restrict__ Xb, const ushort* __restrict__ Wb,
    const float* __restrict__ bo, float* __restrict__ out)
{
    __shared__ ushort Xs[128][72];   // 18,432 B  [row][e-in-chunk]
    __shared__ ushort Ws[128][72];   // 18,432 B  [f-local][e-in-chunk]
    const int b = blockIdx.x;
    const int by = b >> 3, bx = b & 7;
    const int r0 = by * 128, f0 = bx * 128;
    const int tid = threadIdx.x;
    const int wid = tid >> 6, lane = tid & 63;
    const int wr = wid >> 2, wc = wid & 3;
    const int lr = lane & 15, lk = lane >> 4;

    f32x4 acc[4][2];
#pragma unroll
    for (int rt = 0; rt < 4; ++rt)
#pragma unroll
        for (int ft = 0; ft < 2; ++ft)
#pragma unroll
            for (int rg = 0; rg < 4; ++rg) acc[rt][ft][rg] = 0.f;

    // staging map: row = tid>>2, 16-bf16 quarter = (tid&3)*16
    const int sr = tid >> 2, sc = (tid & 3) * 16;
    const int sR = r0 + sr;
    const int sn = sR >> 9, sq = (sR >> 1) & 255, ss2 = sR & 1;

#pragma unroll 1
    for (int eo = 0; eo < 1024; eo += 64) {
        const int hr = eo >> 7, sp = (eo >> 6) & 1;
        __syncthreads();
        {
            long xo = ((long)((sn * 16 + (ss2 * 8 + hr)) * 2 + sp)) * 16384 +
                      sq * 64 + sc;
            *(uint4*)&Xs[sr][sc] = *(const uint4*)(Xb + xo);
            *(uint4*)&Xs[sr][sc + 8] = *(const uint4*)(Xb + xo + 8);
            long wo = (long)(f0 + sr) * 1024 + eo + sc;
            *(uint4*)&Ws[sr][sc] = *(const uint4*)(Wb + wo);
            *(uint4*)&Ws[sr][sc + 8] = *(const uint4*)(Wb + wo + 8);
        }
        __syncthreads();

#pragma unroll
        for (int ks = 0; ks < 2; ++ks) {
            bf16x8 a[4], bb[2];
#pragma unroll
            for (int rt = 0; rt < 4; ++rt)
                a[rt] = *(const bf16x8*)
                    &Xs[wr * 64 + rt * 16 + lr][ks * 32 + lk * 8];
#pragma unroll
            for (int ft = 0; ft < 2; ++ft)
                bb[ft] = *(const bf16x8*)
                    &Ws[wc * 32 + ft * 16 + lr][ks * 32 + lk * 8];
#pragma unroll
            for (int rt = 0; rt < 4; ++rt)
#pragma unroll
                for (int ft = 0; ft < 2; ++ft)
                    acc[rt][ft] = __builtin_amdgcn_mfma_f32_16x16x32_bf16(
                        a[rt], bb[ft], acc[rt][ft], 0, 0, 0);
        }
    }

    // epilogue: D col=lane&15 (=f), row=(lane>>4)*4+reg (=r)
#pragma unroll
    for (int ft = 0; ft < 2; ++ft) {
        const int f = f0 + wc * 32 + ft * 16 + lr;
        const float bias = bo[f];
#pragma unroll
        for (int rt = 0; rt < 4; ++rt) {
#pragma unroll
            for (int rg = 0; rg < 4; ++rg) {
                const int r = r0 + wr * 64 + rt * 16 + lk * 4 + rg;
                out[(long)r * 1024 + f] = acc[rt][ft][rg] + bias;
            }
        }
    }
}

extern "C" void kernel_launch(void* const* d_in, const int* in_sizes, int n_in,
                              void* d_out, int out_size, void* d_ws,
                              size_t ws_size, hipStream_t stream)
{
    const float* vals = (const float*)d_in[0];
    const float* keys = (const float*)d_in[1];
    const float* qrys = (const float*)d_in[2];
    const int*   mask = (const int*)d_in[3];
    const float* Wv   = (const float*)d_in[4];
    const float* Wk   = (const float*)d_in[5];
    const float* Wq   = (const float*)d_in[6];
    const float* Wo   = (const float*)d_in[7];
    const float* bo   = (const float*)d_in[8];
    float* ws  = (float*)d_ws;
    float* vP  = ws;
    float* kP  = ws + 8388608;
    float* qP  = ws + 16777216;
    ushort* Xb = (ushort*)(ws + 25165824);
    float2* St = (float2*)(ws + 33554432);
    ushort* Wb = (ushort*)(ws + 33816576);
    float* out = (float*)d_out;

    k_wot  <<<1024, 256, 0, stream>>>(Wo, Wb);
    k_proj <<<2048, 256, 0, stream>>>(vals, keys, qrys, Wv, Wk, Wq, vP, kP, qP);
    k_stats<<<1024, 512, 0, stream>>>(kP, qP, mask, St);
    k_pv2  <<<1024, 512, 0, stream>>>(kP, qP, vP, mask, St, Xb);
    k_wo   <<< 512, 512, 0, stream>>>(Xb, Wb, bo, out);
}

// Round 18
// 259.093 us; speedup vs baseline: 3.5940x; 1.8416x over previous
//
#include <hip/hip_runtime.h>

// EntailmentSelfAttention: N=16, L=256, S=2, H=16, D=64, E=1024
//
// Pipeline (5 kernels):
//   K0 k_wot   : Wb[f][e'] = bf16(Wo[f][perm(e')]) (frozen, r17).
//   K1 k_proj  : projections -> kP,qP (f32, for k_stats) + kB,qB,vB (bf16,
//                for MFMA k_pv2). f32 vP write dropped (no consumer).
//   K2 k_stats : frozen f32 (r11 shape). Produces St = (m, 1/Z).
//   K3 k_pv2   : NOW bf16 MFMA (r17 measured it at 282us = 60% of total,
//                f32 SIMT ~60TF; r17's k_wo proved MFMA >=5x on this shape).
//                Per (nhs, qblk=128q): 8 waves, wave = one 16q tile.
//                Per l-slab(32): stage Ks[32][72], vsT[64][40] (V transposed
//                so PV B-frags are contiguous), sst; S^T = Q*K^T via 4 MFMA
//                (D col=l, row=q; mask bit wave-uniform per q-tile);
//                att = exp(sv-m)*invZ -> bf16 atts[128][40]; PV = atts*vsT
//                via 4 MFMA (K=32, one instr), acc f32 across slabs.
//                LDS 38.7KB -> 4 blocks/CU. Numerics: scale=1/32 shrinks
//                bf16 dot error to ~3e-4 in s -> att rel err ~3e-4; curr
//                absmax 9.8e-4, threshold 4.27e-3.
//   K4 k_wo    : bf16 MFMA GEMM (frozen, r17; reads Xb).
//
// ws layout (f32-elem offsets): kP @0, qP @8388608, kB(bf16) @16777216,
//   qB @20971520, vB @25165824, Xb @29360128, St @33554432, Wb @33816576.

typedef __attribute__((ext_vector_type(8))) short bf16x8;
typedef __attribute__((ext_vector_type(4))) float f32x4;

__device__ inline ushort f2bf(float x) {
    uint u = __float_as_uint(x);
    u += 0x7FFFu + ((u >> 16) & 1u);
    return (ushort)(u >> 16);
}

__global__ __launch_bounds__(256) void k_wot(
    const float* __restrict__ Wo, ushort* __restrict__ Wb)
{
    const int f = blockIdx.x;          // 0..1023
    const int e4 = threadIdx.x * 4;    // e' base (d%4==0, fixed hr/sp)
    const int hr = e4 >> 7, sp = (e4 >> 6) & 1, d = e4 & 63;
    const float* wrow = Wo + (long)f * 1024 + hr * 128 + 2 * d + sp;
    ushort o[4] = {f2bf(wrow[0]), f2bf(wrow[2]), f2bf(wrow[4]), f2bf(wrow[6])};
    *(uint2*)(Wb + (long)f * 1024 + e4) = *(uint2*)o;
}

__global__ __launch_bounds__(256) void k_proj(
    const float* __restrict__ Av, const float* __restrict__ Ak,
    const float* __restrict__ Aq, const float* __restrict__ Wv,
    const float* __restrict__ Wk, const float* __restrict__ Wq,
    float* __restrict__ kP, float* __restrict__ qP,
    ushort* __restrict__ kB, ushort* __restrict__ qB,
    ushort* __restrict__ vB)
{
    __shared__ float As[3][64][36];
    __shared__ float Ws[3][64][36];
    const int b = blockIdx.x;
    const int h = b & 15, s = (b >> 4) & 1, lblk = (b >> 5) & 3, n = b >> 7;
    const int l0 = lblk * 64;
    const float* Asrc[3] = {Av, Ak, Aq};
    const float* Wsrc[3] = {Wv, Wk, Wq};
    const int tid = threadIdx.x;
    const int ty = tid >> 4, tx = tid & 15;

    float acc[3][4][4];
#pragma unroll
    for (int m = 0; m < 3; ++m)
#pragma unroll
        for (int i = 0; i < 4; ++i)
#pragma unroll
            for (int j = 0; j < 4; ++j) acc[m][i][j] = 0.f;

    const long baseA = (long)n * 524288 + (long)l0 * 2048 + s * 1024 + h * 64;

#pragma unroll
    for (int k0 = 0; k0 < 64; k0 += 32) {
        __syncthreads();
#pragma unroll
        for (int m = 0; m < 3; ++m) {
#pragma unroll
            for (int w = 0; w < 2; ++w) {
                int idx = w * 1024 + tid * 4;
                int r = idx >> 5, c = idx & 31;
                *(float4*)&As[m][r][c] =
                    *(const float4*)(Asrc[m] + baseA + (long)r * 2048 + k0 + c);
                *(float4*)&Ws[m][r][c] =
                    *(const float4*)(Wsrc[m] + r * 64 + k0 + c);
            }
        }
        __syncthreads();
#pragma unroll
        for (int kk = 0; kk < 32; kk += 4) {
            float4 a[3][4], wb[3][4];
#pragma unroll
            for (int m = 0; m < 3; ++m)
#pragma unroll
                for (int i = 0; i < 4; ++i)
                    a[m][i] = *(const float4*)&As[m][ty + 16 * i][kk];
#pragma unroll
            for (int m = 0; m < 3; ++m)
#pragma unroll
                for (int j = 0; j < 4; ++j)
                    wb[m][j] = *(const float4*)&Ws[m][tx + 16 * j][kk];
#pragma unroll
            for (int m = 0; m < 3; ++m)
#pragma unroll
                for (int i = 0; i < 4; ++i)
#pragma unroll
                    for (int j = 0; j < 4; ++j) {
                        acc[m][i][j] += a[m][i].x * wb[m][j].x;
                        acc[m][i][j] += a[m][i].y * wb[m][j].y;
                        acc[m][i][j] += a[m][i].z * wb[m][j].z;
                        acc[m][i][j] += a[m][i].w * wb[m][j].w;
                    }
        }
    }

    const long pbase = ((long)((n * 16 + h) * 2 + s)) * 16384 + (long)l0 * 64;
    ushort* Bdst[3] = {vB, kB, qB};
#pragma unroll
    for (int m = 0; m < 3; ++m)
#pragma unroll
        for (int i = 0; i < 4; ++i)
#pragma unroll
            for (int j = 0; j < 4; ++j) {
                const long off = pbase + (ty + 16 * i) * 64 + tx + 16 * j;
                const float v = acc[m][i][j];
                Bdst[m][off] = f2bf(v);
                if (m == 1) kP[off] = v;
                if (m == 2) qP[off] = v;
            }
}

// Stats pass (frozen f32): block = (nhs, lhalf of 128 l), 512 thr.
__global__ __launch_bounds__(512, 4) void k_stats(
    const float* __restrict__ kP, const float* __restrict__ qP,
    const int* __restrict__ mask, float2* __restrict__ St)
{
    __shared__ float Ks[128][68];    // 34,816 B
    __shared__ float Qs[32][68];     //  8,704 B
    __shared__ float atts[32][132];  // 16,896 B
    const int b = blockIdx.x;
    const int nhs = b >> 1, lblk = b & 1;
    const int n = nhs >> 5, h = (nhs >> 1) & 15, s = nhs & 1;
    const long slice = (long)nhs * 16384;
    const int l0 = lblk * 128;
    const int tid = threadIdx.x;
    const int tyS = tid >> 4, tx = tid & 15;   // tyS 0..31

#pragma unroll
    for (int w = 0; w < 4; ++w) {
        int r = w * 32 + tyS, c = tx * 4;
        *(float4*)&Ks[r][c] = *(const float4*)(kP + slice + (l0 + r) * 64 + c);
    }

    const int mrow = n * 524288 + (h >> 3) * 262144 + (h & 7) * 32 + s * 16;
    const float scale = 0.03125f;  // 1/sqrt(1024)
    float zrun = 0.f;              // threads<128: running Z for l = l0+tid

#pragma unroll 1
    for (int qs = 0; qs < 8; ++qs) {
        __syncthreads();  // Ks ready (qs=0) / prev atts consumed by reduce
        {
            int r = tyS, c = tx * 4;
            *(float4*)&Qs[r][c] =
                *(const float4*)(qP + slice + (qs * 32 + r) * 64 + c);
        }
        __syncthreads();

        const int q = qs * 32 + tyS;
        const float live = (mask[mrow + (q >> 4)] != 0) ? 1.f : 0.f;

#pragma unroll
        for (int jh = 0; jh < 2; ++jh) {
            float satt[4];
#pragma unroll
            for (int jj = 0; jj < 4; ++jj) satt[jj] = 0.f;
#pragma unroll
            for (int kk = 0; kk < 64; kk += 4) {
                float4 a = *(const float4*)&Qs[tyS][kk];
                float4 bk[4];
#pragma unroll
                for (int jj = 0; jj < 4; ++jj)
                    bk[jj] = *(const float4*)&Ks[tx + 16 * (jh * 4 + jj)][kk];
#pragma unroll
                for (int jj = 0; jj < 4; ++jj) {
                    satt[jj] += a.x * bk[jj].x;
                    satt[jj] += a.y * bk[jj].y;
                    satt[jj] += a.z * bk[jj].z;
                    satt[jj] += a.w * bk[jj].w;
                }
            }
#pragma unroll
            for (int jj = 0; jj < 4; ++jj) {
                const int lp = tx + 16 * (jh * 4 + jj);
                atts[tyS][lp] =
                    (live != 0.f) ? expf(satt[jj] * scale) : 0.f;
            }
        }
        __syncthreads();

        if (tid < 128) {
            float zz = 0.f;
#pragma unroll
            for (int r = 0; r < 32; ++r) zz += atts[r][tid];
            zrun += zz;
        }
    }

    if (tid < 128) {
        float2 st = (zrun > 0.f) ? make_float2(0.f, 1.0f / zrun)
                                 : make_float2(-3.125e18f, 1.0f / 256.0f);
        St[nhs * 256 + l0 + tid] = st;
    }
}

// MFMA PV pass: block = (nhs, qblk of 128 q), 512 thr = 8 waves, wave owns
// one 16-q tile (qt = wid). Per l-slab of 32: S^T (4 MFMA) -> exp -> atts
// bf16 -> PV (4 MFMA, K=32). acc f32x4[4] across slabs. LDS 38.7 KB.
__global__ __launch_bounds__(512, 4) void k_pv2(
    const ushort* __restrict__ kB, const ushort* __restrict__ qB,
    const ushort* __restrict__ vB, const int* __restrict__ mask,
    const float2* __restrict__ St, ushort* __restrict__ Xb)
{
    __shared__ ushort Qs[128][72];    // 18,432 B  [q][k]
    __shared__ ushort Ks[32][72];     //  4,608 B  [l][k]
    __shared__ ushort vsT[64][40];    //  5,120 B  [d][l]
    __shared__ ushort atts[128][40];  // 10,240 B  [q][l]
    __shared__ float2 sst[32];        //    256 B
    __shared__ int mb8[8];
    const int b = blockIdx.x;
    const int nhs = b >> 1, qblk = b & 1;
    const int n = nhs >> 5, h = (nhs >> 1) & 15, s = nhs & 1;
    const long slice = (long)nhs * 16384;
    const int q0 = qblk * 128;
    const int tid = threadIdx.x;
    const int wid = tid >> 6, lane = tid & 63;
    const int lr = lane & 15, lk = lane >> 4;
    const int qt = wid;   // wave's 16-q tile

    // stage Q tile (128x64 bf16): 1024 uint4-chunks of 8, 2/thread
#pragma unroll
    for (int w = 0; w < 2; ++w) {
        int idx = w * 512 + tid;
        int r = idx >> 3, c8 = (idx & 7) * 8;
        *(uint4*)&Qs[r][c8] =
            *(const uint4*)(qB + slice + (q0 + r) * 64 + c8);
    }
    const int mrow = n * 524288 + (h >> 3) * 262144 + (h & 7) * 32 + s * 16;
    if (tid < 8) mb8[tid] = mask[mrow + qblk * 8 + tid];

    f32x4 acc[4];
#pragma unroll
    for (int dt = 0; dt < 4; ++dt)
#pragma unroll
        for (int rg = 0; rg < 4; ++rg) acc[dt][rg] = 0.f;

    const float scale = 0.03125f;

#pragma unroll 1
    for (int sl = 0; sl < 8; ++sl) {
        __syncthreads();  // prev PV done with Ks/vsT/atts; Qs ready (sl=0)
        // stage K slab (32x64): 256 chunks, threads <256
        if (tid < 256) {
            int r = tid >> 3, c8 = (tid & 7) * 8;
            *(uint4*)&Ks[r][c8] =
                *(const uint4*)(kB + slice + (sl * 32 + r) * 64 + c8);
        }
        // stage V transposed: thread loads 4 bf16 of row l, scatters to vsT
        {
            int l = tid >> 4, d4 = (tid & 15) * 4;
            uint2 vv = *(const uint2*)(vB + slice + (sl * 32 + l) * 64 + d4);
            ushort t4[4];
            *(uint2*)t4 = vv;
            vsT[d4 + 0][l] = t4[0];
            vsT[d4 + 1][l] = t4[1];
            vsT[d4 + 2][l] = t4[2];
            vsT[d4 + 3][l] = t4[3];
        }
        if (tid < 32) sst[tid] = St[nhs * 256 + sl * 32 + tid];
        __syncthreads();

        // ---- S^T MFMA: M=q(16, this wave), N=l(32: 2 tiles), K=64(2 steps)
        bf16x8 a0 = *(const bf16x8*)&Qs[qt * 16 + lr][lk * 8];
        bf16x8 a1 = *(const bf16x8*)&Qs[qt * 16 + lr][32 + lk * 8];
        f32x4 sacc[2];
#pragma unroll
        for (int lt = 0; lt < 2; ++lt) {
#pragma unroll
            for (int rg = 0; rg < 4; ++rg) sacc[lt][rg] = 0.f;
            bf16x8 b0 = *(const bf16x8*)&Ks[lt * 16 + lr][lk * 8];
            bf16x8 b1 = *(const bf16x8*)&Ks[lt * 16 + lr][32 + lk * 8];
            sacc[lt] = __builtin_amdgcn_mfma_f32_16x16x32_bf16(
                a0, b0, sacc[lt], 0, 0, 0);
            sacc[lt] = __builtin_amdgcn_mfma_f32_16x16x32_bf16(
                a1, b1, sacc[lt], 0, 0, 0);
        }
        // mask/exp/invZ -> atts bf16. D: col=l=lr(+16lt), row=q=lk*4+rg.
        const bool live = (mb8[qt] != 0);   // wave-uniform
#pragma unroll
        for (int lt = 0; lt < 2; ++lt) {
            const int l = lt * 16 + lr;
            const float2 st = sst[l];
#pragma unroll
            for (int rg = 0; rg < 4; ++rg) {
                float sv = live ? sacc[lt][rg] * scale : -3.125e18f;
                float av = expf(sv - st.x) * st.y;
                atts[qt * 16 + lk * 4 + rg][l] = f2bf(av);
            }
        }
        __syncthreads();

        // ---- PV MFMA: M=q(16), N=d(64: 4 tiles), K=32(l, one instr)
        bf16x8 aP = *(const bf16x8*)&atts[qt * 16 + lr][lk * 8];
#pragma unroll
        for (int dt = 0; dt < 4; ++dt) {
            bf16x8 bV = *(const bf16x8*)&vsT[dt * 16 + lr][lk * 8];
            acc[dt] = __builtin_amdgcn_mfma_f32_16x16x32_bf16(
                aP, bV, acc[dt], 0, 0, 0);
        }
    }

    // epilogue: D col=d=lr(+16dt), row=q=lk*4+rg -> Xb[nhs][q0+q][d]
#pragma unroll
    for (int dt = 0; dt < 4; ++dt) {
#pragma unroll
        for (int rg = 0; rg < 4; ++rg) {
            const int q = q0 + qt * 16 + lk * 4 + rg;
            const int d = dt * 16 + lr;
            Xb[slice + (long)q * 64 + d] = f2bf(acc[dt][rg]);
        }
    }
}

// MFMA k_wo (frozen, r17): out[R][f] = sum_e' X'[R][e'] Wb[f][e'] + bo[f].
__global__ __launch_bounds__(512) void k_wo(
    const ushort* __restrict__ Xb, const ushort* __restrict__ Wb,
    const float* __restrict__ bo, float* __restrict__ out)
{
    __shared__ ushort Xs[128][72];   // 18,432 B  [row][e-in-chunk]
    __shared__ ushort Ws[128][72];   // 18,432 B  [f-local][e-in-chunk]
    const int b = blockIdx.x;
    const int by = b >> 3, bx = b & 7;
    const int r0 = by * 128, f0 = bx * 128;
    const int tid = threadIdx.x;
    const int wid = tid >> 6, lane = tid & 63;
    const int wr = wid >> 2, wc = wid & 3;
    const int lr = lane & 15, lk = lane >> 4;

    f32x4 acc[4][2];
#pragma unroll
    for (int rt = 0; rt < 4; ++rt)
#pragma unroll
        for (int ft = 0; ft < 2; ++ft)
#pragma unroll
            for (int rg = 0; rg < 4; ++rg) acc[rt][ft][rg] = 0.f;

    const int sr = tid >> 2, sc = (tid & 3) * 16;
    const int sR = r0 + sr;
    const int sn = sR >> 9, sq = (sR >> 1) & 255, ss2 = sR & 1;

#pragma unroll 1
    for (int eo = 0; eo < 1024; eo += 64) {
        const int hr = eo >> 7, sp = (eo >> 6) & 1;
        __syncthreads();
        {
            long xo = ((long)((sn * 16 + (ss2 * 8 + hr)) * 2 + sp)) * 16384 +
                      sq * 64 + sc;
            *(uint4*)&Xs[sr][sc] = *(const uint4*)(Xb + xo);
            *(uint4*)&Xs[sr][sc + 8] = *(const uint4*)(Xb + xo + 8);
            long wo = (long)(f0 + sr) * 1024 + eo + sc;
            *(uint4*)&Ws[sr][sc] = *(const uint4*)(Wb + wo);
            *(uint4*)&Ws[sr][sc + 8] = *(const uint4*)(Wb + wo + 8);
        }
        __syncthreads();

#pragma unroll
        for (int ks = 0; ks < 2; ++ks) {
            bf16x8 a[4], bb[2];
#pragma unroll
            for (int rt = 0; rt < 4; ++rt)
                a[rt] = *(const bf16x8*)
                    &Xs[wr * 64 + rt * 16 + lr][ks * 32 + lk * 8];
#pragma unroll
            for (int ft = 0; ft < 2; ++ft)
                bb[ft] = *(const bf16x8*)
                    &Ws[wc * 32 + ft * 16 + lr][ks * 32 + lk * 8];
#pragma unroll
            for (int rt = 0; rt < 4; ++rt)
#pragma unroll
                for (int ft = 0; ft < 2; ++ft)
                    acc[rt][ft] = __builtin_amdgcn_mfma_f32_16x16x32_bf16(
                        a[rt], bb[ft], acc[rt][ft], 0, 0, 0);
        }
    }

#pragma unroll
    for (int ft = 0; ft < 2; ++ft) {
        const int f = f0 + wc * 32 + ft * 16 + lr;
        const float bias = bo[f];
#pragma unroll
        for (int rt = 0; rt < 4; ++rt) {
#pragma unroll
            for (int rg = 0; rg < 4; ++rg) {
                const int r = r0 + wr * 64 + rt * 16 + lk * 4 + rg;
                out[(long)r * 1024 + f] = acc[rt][ft][rg] + bias;
            }
        }
    }
}

extern "C" void kernel_launch(void* const* d_in, const int* in_sizes, int n_in,
                              void* d_out, int out_size, void* d_ws,
                              size_t ws_size, hipStream_t stream)
{
    const float* vals = (const float*)d_in[0];
    const float* keys = (const float*)d_in[1];
    const float* qrys = (const float*)d_in[2];
    const int*   mask = (const int*)d_in[3];
    const float* Wv   = (const float*)d_in[4];
    const float* Wk   = (const float*)d_in[5];
    const float* Wq   = (const float*)d_in[6];
    const float* Wo   = (const float*)d_in[7];
    const float* bo   = (const float*)d_in[8];
    float* ws  = (float*)d_ws;
    float*  kP = ws;
    float*  qP = ws + 8388608;
    ushort* kB = (ushort*)(ws + 16777216);
    ushort* qB = (ushort*)(ws + 20971520);
    ushort* vB = (ushort*)(ws + 25165824);
    ushort* Xb = (ushort*)(ws + 29360128);
    float2* St = (float2*)(ws + 33554432);
    ushort* Wb = (ushort*)(ws + 33816576);
    float* out = (float*)d_out;

    k_wot  <<<1024, 256, 0, stream>>>(Wo, Wb);
    k_proj <<<2048, 256, 0, stream>>>(vals, keys, qrys, Wv, Wk, Wq,
                                      kP, qP, kB, qB, vB);
    k_stats<<<1024, 512, 0, stream>>>(kP, qP, mask, St);
    k_pv2  <<<1024, 512, 0, stream>>>(kB, qB, vB, mask, St, Xb);
    k_wo   <<< 512, 512, 0, stream>>>(Xb, Wb, bo, out);
}

// Round 19
// 151.245 us; speedup vs baseline: 6.1568x; 1.7131x over previous
//
#include <hip/hip_runtime.h>

// EntailmentSelfAttention: N=16, L=256, S=2, H=16, D=64, E=1024
//
// Pipeline (4 kernels):
//   K0 k_wot  : Wb[f][e'] = bf16(Wo[f][perm(e')]) (frozen, r17).
//   K1 k_proj : projections -> kB,qB,vB bf16 only (f32 kP/qP dropped).
//   K2 k_attn : FUSED stats+PV per nhs (all 256 q); k_stats deleted.
//               r18: stats=145us (56% of total) solely to compute
//               Z_l = sum_q exp(s). Here: phase 1 computes S^T via MFMA,
//               E=exp(s*scale) (no max pass, r8-proven; masked -> 0),
//               accumulates Z[l] via LDS atomicAdd (unique-ish writers,
//               fp32); phase 2 recomputes S^T, att = E*invZ -> bf16,
//               PV MFMA. S computed twice here but both on matrix cores
//               (r17/r18 proved ~5x density); kP/qP f32 traffic gone.
//               LDS 53KB -> 2 blocks/CU (Qs 36.9K + Ks 4.6K + vsT 5.1K +
//               Es 5.1K + invZ 1K + mb 64B), 8 waves/block.
//   K3 k_wo   : bf16 MFMA GEMM (frozen, r17).
//
// ws layout (f32-elem offsets): kB @0, qB @4194304, vB @8388608,
//   Xb @12582912, Wb @16777216.

typedef __attribute__((ext_vector_type(8))) short bf16x8;
typedef __attribute__((ext_vector_type(4))) float f32x4;

__device__ inline ushort f2bf(float x) {
    uint u = __float_as_uint(x);
    u += 0x7FFFu + ((u >> 16) & 1u);
    return (ushort)(u >> 16);
}

__global__ __launch_bounds__(256) void k_wot(
    const float* __restrict__ Wo, ushort* __restrict__ Wb)
{
    const int f = blockIdx.x;          // 0..1023
    const int e4 = threadIdx.x * 4;    // e' base (d%4==0, fixed hr/sp)
    const int hr = e4 >> 7, sp = (e4 >> 6) & 1, d = e4 & 63;
    const float* wrow = Wo + (long)f * 1024 + hr * 128 + 2 * d + sp;
    ushort o[4] = {f2bf(wrow[0]), f2bf(wrow[2]), f2bf(wrow[4]), f2bf(wrow[6])};
    *(uint2*)(Wb + (long)f * 1024 + e4) = *(uint2*)o;
}

__global__ __launch_bounds__(256) void k_proj(
    const float* __restrict__ Av, const float* __restrict__ Ak,
    const float* __restrict__ Aq, const float* __restrict__ Wv,
    const float* __restrict__ Wk, const float* __restrict__ Wq,
    ushort* __restrict__ kB, ushort* __restrict__ qB,
    ushort* __restrict__ vB)
{
    __shared__ float As[3][64][36];
    __shared__ float Ws[3][64][36];
    const int b = blockIdx.x;
    const int h = b & 15, s = (b >> 4) & 1, lblk = (b >> 5) & 3, n = b >> 7;
    const int l0 = lblk * 64;
    const float* Asrc[3] = {Av, Ak, Aq};
    const float* Wsrc[3] = {Wv, Wk, Wq};
    const int tid = threadIdx.x;
    const int ty = tid >> 4, tx = tid & 15;

    float acc[3][4][4];
#pragma unroll
    for (int m = 0; m < 3; ++m)
#pragma unroll
        for (int i = 0; i < 4; ++i)
#pragma unroll
            for (int j = 0; j < 4; ++j) acc[m][i][j] = 0.f;

    const long baseA = (long)n * 524288 + (long)l0 * 2048 + s * 1024 + h * 64;

#pragma unroll
    for (int k0 = 0; k0 < 64; k0 += 32) {
        __syncthreads();
#pragma unroll
        for (int m = 0; m < 3; ++m) {
#pragma unroll
            for (int w = 0; w < 2; ++w) {
                int idx = w * 1024 + tid * 4;
                int r = idx >> 5, c = idx & 31;
                *(float4*)&As[m][r][c] =
                    *(const float4*)(Asrc[m] + baseA + (long)r * 2048 + k0 + c);
                *(float4*)&Ws[m][r][c] =
                    *(const float4*)(Wsrc[m] + r * 64 + k0 + c);
            }
        }
        __syncthreads();
#pragma unroll
        for (int kk = 0; kk < 32; kk += 4) {
            float4 a[3][4], wb[3][4];
#pragma unroll
            for (int m = 0; m < 3; ++m)
#pragma unroll
                for (int i = 0; i < 4; ++i)
                    a[m][i] = *(const float4*)&As[m][ty + 16 * i][kk];
#pragma unroll
            for (int m = 0; m < 3; ++m)
#pragma unroll
                for (int j = 0; j < 4; ++j)
                    wb[m][j] = *(const float4*)&Ws[m][tx + 16 * j][kk];
#pragma unroll
            for (int m = 0; m < 3; ++m)
#pragma unroll
                for (int i = 0; i < 4; ++i)
#pragma unroll
                    for (int j = 0; j < 4; ++j) {
                        acc[m][i][j] += a[m][i].x * wb[m][j].x;
                        acc[m][i][j] += a[m][i].y * wb[m][j].y;
                        acc[m][i][j] += a[m][i].z * wb[m][j].z;
                        acc[m][i][j] += a[m][i].w * wb[m][j].w;
                    }
        }
    }

    const long pbase = ((long)((n * 16 + h) * 2 + s)) * 16384 + (long)l0 * 64;
    ushort* Bdst[3] = {vB, kB, qB};
#pragma unroll
    for (int m = 0; m < 3; ++m)
#pragma unroll
        for (int i = 0; i < 4; ++i)
#pragma unroll
            for (int j = 0; j < 4; ++j)
                Bdst[m][pbase + (ty + 16 * i) * 64 + tx + 16 * j] =
                    f2bf(acc[m][i][j]);
}

// Fused stats+PV: one block per nhs (all 256 q), 512 thr = 8 waves; wave
// owns q-strip [wid*32, +32) as two 16-q tiles with separate accumulators.
__global__ __launch_bounds__(512) void k_attn(
    const ushort* __restrict__ kB, const ushort* __restrict__ qB,
    const ushort* __restrict__ vB, const int* __restrict__ mask,
    ushort* __restrict__ Xb)
{
    __shared__ ushort Qs[256][72];    // 36,864 B  [q][k]
    __shared__ ushort Ks[32][72];     //  4,608 B  [l][k]
    __shared__ ushort vsT[64][40];    //  5,120 B  [d][l]
    __shared__ ushort Es[128][40];    // 10,240 B  [q-half][l] (wave qt pack)
    __shared__ float Zl[256];         //  1,024 B  Z accumulator (atomicAdd)
    __shared__ int mb16[16];
    const int nhs = blockIdx.x;
    const int n = nhs >> 5, h = (nhs >> 1) & 15, s = nhs & 1;
    const long slice = (long)nhs * 16384;
    const int tid = threadIdx.x;
    const int wid = tid >> 6, lane = tid & 63;
    const int lr = lane & 15, lk = lane >> 4;

    // stage Q (256x64): 2048 chunks of 8 bf16, 4/thread
#pragma unroll
    for (int w = 0; w < 4; ++w) {
        int idx = w * 512 + tid;
        int r = idx >> 3, c8 = (idx & 7) * 8;
        *(uint4*)&Qs[r][c8] = *(const uint4*)(qB + slice + r * 64 + c8);
    }
    const int mrow = n * 524288 + (h >> 3) * 262144 + (h & 7) * 32 + s * 16;
    if (tid < 16) mb16[tid] = mask[mrow + tid];
    if (tid < 256) Zl[tid] = 0.f;

    const float scale = 0.03125f;

    // ========== PHASE 1: Z accumulation ==========
#pragma unroll 1
    for (int sl = 0; sl < 8; ++sl) {
        __syncthreads();   // Qs/Zl/mb16 ready (sl=0) / prev Ks consumed
        if (tid < 256) {
            int r = tid >> 3, c8 = (tid & 7) * 8;
            *(uint4*)&Ks[r][c8] =
                *(const uint4*)(kB + slice + (sl * 32 + r) * 64 + c8);
        }
        __syncthreads();

#pragma unroll
        for (int qt = 0; qt < 2; ++qt) {
            const int qb = wid * 32 + qt * 16;
            const bool live = (mb16[qb >> 4] != 0);
            if (!live) continue;   // masked 16q contributes 0 to every Z_l
            bf16x8 a0 = *(const bf16x8*)&Qs[qb + lr][lk * 8];
            bf16x8 a1 = *(const bf16x8*)&Qs[qb + lr][32 + lk * 8];
#pragma unroll
            for (int lt = 0; lt < 2; ++lt) {
                f32x4 sacc;
#pragma unroll
                for (int rg = 0; rg < 4; ++rg) sacc[rg] = 0.f;
                bf16x8 b0 = *(const bf16x8*)&Ks[lt * 16 + lr][lk * 8];
                bf16x8 b1 = *(const bf16x8*)&Ks[lt * 16 + lr][32 + lk * 8];
                sacc = __builtin_amdgcn_mfma_f32_16x16x32_bf16(
                    a0, b0, sacc, 0, 0, 0);
                sacc = __builtin_amdgcn_mfma_f32_16x16x32_bf16(
                    a1, b1, sacc, 0, 0, 0);
                // D: col=l=lt*16+lr, row=q=qb+lk*4+rg
                float zq = 0.f;
#pragma unroll
                for (int rg = 0; rg < 4; ++rg)
                    zq += __expf(sacc[rg] * scale);
                atomicAdd(&Zl[sl * 32 + lt * 16 + lr], zq);
            }
        }
    }

    __syncthreads();
    if (tid < 256) {
        float z = Zl[tid];
        Zl[tid] = (z > 0.f) ? 1.0f / z : 1.0f / 256.0f;
    }

    // ========== PHASE 2: att + PV ==========
    f32x4 acc0[4], acc1[4];
#pragma unroll
    for (int dt = 0; dt < 4; ++dt)
#pragma unroll
        for (int rg = 0; rg < 4; ++rg) { acc0[dt][rg] = 0.f; acc1[dt][rg] = 0.f; }

#pragma unroll 1
    for (int sl = 0; sl < 8; ++sl) {
        __syncthreads();   // Zl ready (sl=0) / prev Ks,vsT,Es consumed
        if (tid < 256) {
            int r = tid >> 3, c8 = (tid & 7) * 8;
            *(uint4*)&Ks[r][c8] =
                *(const uint4*)(kB + slice + (sl * 32 + r) * 64 + c8);
        } else {
            int t = tid - 256;
            int l = t >> 3, d8 = (t & 7) * 8;
            uint4 vv = *(const uint4*)(vB + slice + (sl * 32 + l) * 64 + d8);
            ushort t8[8];
            *(uint4*)t8 = vv;
#pragma unroll
            for (int u = 0; u < 8; ++u) vsT[d8 + u][l] = t8[u];
        }
        __syncthreads();

        // att for both q-tiles of this wave -> Es rows [wid*16 + ...] per qt
        // Es layout: [128][40]: row = wid*16 + (q%16), one 128-row half per
        // qt pass (qt=0 uses rows 0..127? NO). Simpler: Es indexed by
        // wave-local row = wid*16 + lk*4+rg, reused per qt (barrier between).
#pragma unroll
        for (int qt = 0; qt < 2; ++qt) {
            const int qb = wid * 32 + qt * 16;
            const bool live = (mb16[qb >> 4] != 0);
            bf16x8 a0 = *(const bf16x8*)&Qs[qb + lr][lk * 8];
            bf16x8 a1 = *(const bf16x8*)&Qs[qb + lr][32 + lk * 8];
#pragma unroll
            for (int lt = 0; lt < 2; ++lt) {
                f32x4 sacc;
#pragma unroll
                for (int rg = 0; rg < 4; ++rg) sacc[rg] = 0.f;
                bf16x8 b0 = *(const bf16x8*)&Ks[lt * 16 + lr][lk * 8];
                bf16x8 b1 = *(const bf16x8*)&Ks[lt * 16 + lr][32 + lk * 8];
                sacc = __builtin_amdgcn_mfma_f32_16x16x32_bf16(
                    a0, b0, sacc, 0, 0, 0);
                sacc = __builtin_amdgcn_mfma_f32_16x16x32_bf16(
                    a1, b1, sacc, 0, 0, 0);
                const int l = lt * 16 + lr;
                const float iz = Zl[sl * 32 + l];
#pragma unroll
                for (int rg = 0; rg < 4; ++rg) {
                    float ev = live ? __expf(sacc[rg] * scale) * iz : 0.f;
                    Es[wid * 16 + lk * 4 + rg][l] = f2bf(ev);
                }
            }
            // Es row block for this wave is private to this wave; the MFMA
            // below reads only rows wid*16..+15 -> wave-local, no barrier
            // needed between write & read within the wave EXCEPT LDS
            // visibility: same wave, s_waitcnt lgkmcnt handles it.
            __builtin_amdgcn_s_waitcnt(0);  // lgkmcnt(0)
            bf16x8 aP = *(const bf16x8*)&Es[wid * 16 + lr][lk * 8];
            f32x4* accp = (qt == 0) ? acc0 : acc1;
#pragma unroll
            for (int dt = 0; dt < 4; ++dt) {
                bf16x8 bV = *(const bf16x8*)&vsT[dt * 16 + lr][lk * 8];
                accp[dt] = __builtin_amdgcn_mfma_f32_16x16x32_bf16(
                    aP, bV, accp[dt], 0, 0, 0);
            }
        }
    }

    // epilogue: D col=d, row=q-local -> Xb[nhs][q][d]
#pragma unroll
    for (int qt = 0; qt < 2; ++qt) {
        const f32x4* accp = (qt == 0) ? acc0 : acc1;
        const int qb = wid * 32 + qt * 16;
#pragma unroll
        for (int dt = 0; dt < 4; ++dt) {
#pragma unroll
            for (int rg = 0; rg < 4; ++rg) {
                const int q = qb + lk * 4 + rg;
                const int d = dt * 16 + lr;
                Xb[slice + (long)q * 64 + d] = f2bf(accp[dt][rg]);
            }
        }
    }
}

// MFMA k_wo (frozen, r17).
__global__ __launch_bounds__(512) void k_wo(
    const ushort* __restrict__ Xb, const ushort* __restrict__ Wb,
    const float* __restrict__ bo, float* __restrict__ out)
{
    __shared__ ushort Xs[128][72];
    __shared__ ushort Ws[128][72];
    const int b = blockIdx.x;
    const int by = b >> 3, bx = b & 7;
    const int r0 = by * 128, f0 = bx * 128;
    const int tid = threadIdx.x;
    const int wid = tid >> 6, lane = tid & 63;
    const int wr = wid >> 2, wc = wid & 3;
    const int lr = lane & 15, lk = lane >> 4;

    f32x4 acc[4][2];
#pragma unroll
    for (int rt = 0; rt < 4; ++rt)
#pragma unroll
        for (int ft = 0; ft < 2; ++ft)
#pragma unroll
            for (int rg = 0; rg < 4; ++rg) acc[rt][ft][rg] = 0.f;

    const int sr = tid >> 2, sc = (tid & 3) * 16;
    const int sR = r0 + sr;
    const int sn = sR >> 9, sq = (sR >> 1) & 255, ss2 = sR & 1;

#pragma unroll 1
    for (int eo = 0; eo < 1024; eo += 64) {
        const int hr = eo >> 7, sp = (eo >> 6) & 1;
        __syncthreads();
        {
            long xo = ((long)((sn * 16 + (ss2 * 8 + hr)) * 2 + sp)) * 16384 +
                      sq * 64 + sc;
            *(uint4*)&Xs[sr][sc] = *(const uint4*)(Xb + xo);
            *(uint4*)&Xs[sr][sc + 8] = *(const uint4*)(Xb + xo + 8);
            long wo = (long)(f0 + sr) * 1024 + eo + sc;
            *(uint4*)&Ws[sr][sc] = *(const uint4*)(Wb + wo);
            *(uint4*)&Ws[sr][sc + 8] = *(const uint4*)(Wb + wo + 8);
        }
        __syncthreads();

#pragma unroll
        for (int ks = 0; ks < 2; ++ks) {
            bf16x8 a[4], bb[2];
#pragma unroll
            for (int rt = 0; rt < 4; ++rt)
                a[rt] = *(const bf16x8*)
                    &Xs[wr * 64 + rt * 16 + lr][ks * 32 + lk * 8];
#pragma unroll
            for (int ft = 0; ft < 2; ++ft)
                bb[ft] = *(const bf16x8*)
                    &Ws[wc * 32 + ft * 16 + lr][ks * 32 + lk * 8];
#pragma unroll
            for (int rt = 0; rt < 4; ++rt)
#pragma unroll
                for (int ft = 0; ft < 2; ++ft)
                    acc[rt][ft] = __builtin_amdgcn_mfma_f32_16x16x32_bf16(
                        a[rt], bb[ft], acc[rt][ft], 0, 0, 0);
        }
    }

#pragma unroll
    for (int ft = 0; ft < 2; ++ft) {
        const int f = f0 + wc * 32 + ft * 16 + lr;
        const float bias = bo[f];
#pragma unroll
        for (int rt = 0; rt < 4; ++rt) {
#pragma unroll
            for (int rg = 0; rg < 4; ++rg) {
                const int r = r0 + wr * 64 + rt * 16 + lk * 4 + rg;
                out[(long)r * 1024 + f] = acc[rt][ft][rg] + bias;
            }
        }
    }
}

extern "C" void kernel_launch(void* const* d_in, const int* in_sizes, int n_in,
                              void* d_out, int out_size, void* d_ws,
                              size_t ws_size, hipStream_t stream)
{
    const float* vals = (const float*)d_in[0];
    const float* keys = (const float*)d_in[1];
    const float* qrys = (const float*)d_in[2];
    const int*   mask = (const int*)d_in[3];
    const float* Wv   = (const float*)d_in[4];
    const float* Wk   = (const float*)d_in[5];
    const float* Wq   = (const float*)d_in[6];
    const float* Wo   = (const float*)d_in[7];
    const float* bo   = (const float*)d_in[8];
    float* ws  = (float*)d_ws;
    ushort* kB = (ushort*)(ws);
    ushort* qB = (ushort*)(ws + 4194304);
    ushort* vB = (ushort*)(ws + 8388608);
    ushort* Xb = (ushort*)(ws + 12582912);
    ushort* Wb = (ushort*)(ws + 16777216);
    float* out = (float*)d_out;

    k_wot <<<1024, 256, 0, stream>>>(Wo, Wb);
    k_proj<<<2048, 256, 0, stream>>>(vals, keys, qrys, Wv, Wk, Wq, kB, qB, vB);
    k_attn<<< 512, 512, 0, stream>>>(kB, qB, vB, mask, Xb);
    k_wo  <<< 512, 512, 0, stream>>>(Xb, Wb, bo, out);
}

// Round 20
// 130.044 us; speedup vs baseline: 7.1605x; 1.1630x over previous
//
#include <hip/hip_runtime.h>

// EntailmentSelfAttention: N=16, L=256, S=2, H=16, D=64, E=1024
//
// Pipeline (4 kernels):
//   K0 k_wot  : Wb[f][e'] = bf16(Wo[f][perm(e')]) (frozen, r17).
//   K1 k_proj : NOW bf16 MFMA (r19: last f32 SIMT GEMM, 72us = 48% of
//               total at the known ~45TF f32 ceiling). One block per
//               (n,h,s) slice; per tensor m: stage A-slice f32->bf16
//               As[256][72] + W->Ws[64][72]; wave owns 64-l strip; 4 l-
//               tiles x 4 e-tiles x K=64 = 32 MFMA; D (col=e,row=l) ->
//               kB/qB/vB. Numerics: projections already stored bf16, so
//               bf16 inputs ~sqrt2-scale an existing error term (K=64,
//               |w|~0.07 -> ~1e-3 added at out; thresh 4.27e-3, curr
//               9.77e-4). LDS 46KB -> 3 blocks/CU.
//   K2 k_attn : fused stats+PV, MFMA (frozen, r19).
//   K3 k_wo   : bf16 MFMA GEMM (frozen, r17).
//
// ws layout (f32-elem offsets): kB @0, qB @4194304, vB @8388608,
//   Xb @12582912, Wb @16777216.

typedef __attribute__((ext_vector_type(8))) short bf16x8;
typedef __attribute__((ext_vector_type(4))) float f32x4;

__device__ inline ushort f2bf(float x) {
    uint u = __float_as_uint(x);
    u += 0x7FFFu + ((u >> 16) & 1u);
    return (ushort)(u >> 16);
}

__global__ __launch_bounds__(256) void k_wot(
    const float* __restrict__ Wo, ushort* __restrict__ Wb)
{
    const int f = blockIdx.x;          // 0..1023
    const int e4 = threadIdx.x * 4;    // e' base (d%4==0, fixed hr/sp)
    const int hr = e4 >> 7, sp = (e4 >> 6) & 1, d = e4 & 63;
    const float* wrow = Wo + (long)f * 1024 + hr * 128 + 2 * d + sp;
    ushort o[4] = {f2bf(wrow[0]), f2bf(wrow[2]), f2bf(wrow[4]), f2bf(wrow[6])};
    *(uint2*)(Wb + (long)f * 1024 + e4) = *(uint2*)o;
}

// MFMA projections: block = (n,h,s) slice; 256 thr = 4 waves.
// Per tensor m in {v,k,q}: stage A (256 l x 64 d, f32->bf16) + W (64x64),
// then out[l][e] = sum_d A[l][d] W[e][d] via 16x16x32 MFMA.
__global__ __launch_bounds__(256) void k_proj(
    const float* __restrict__ Av, const float* __restrict__ Ak,
    const float* __restrict__ Aq, const float* __restrict__ Wv,
    const float* __restrict__ Wk, const float* __restrict__ Wq,
    ushort* __restrict__ kB, ushort* __restrict__ qB,
    ushort* __restrict__ vB)
{
    __shared__ ushort As[256][72];   // 36,864 B  [l][d]
    __shared__ ushort Ws[64][72];    //  9,216 B  [e][d]
    const int b = blockIdx.x;
    const int n = b >> 5, h = (b >> 1) & 15, s = b & 1;
    const float* Asrc[3] = {Av, Ak, Aq};
    const float* Wsrc[3] = {Wv, Wk, Wq};
    const int tid = threadIdx.x;
    const int wid = tid >> 6, lane = tid & 63;
    const int lr = lane & 15, lk = lane >> 4;

    // raw A row l: Asrc + n*524288 + l*2048 + s*1024 + h*64 + d
    const long abase = (long)n * 524288 + s * 1024 + h * 64;
    const long slice = ((long)((n * 16 + h) * 2 + s)) * 16384;
    ushort* Bdst[3] = {vB, kB, qB};

#pragma unroll 1
    for (int m = 0; m < 3; ++m) {
        __syncthreads();   // prev tensor's MFMA reads done
        // stage A: 4096 float4 chunks; idx -> r = idx>>4, c4 = (idx&15)*4
#pragma unroll
        for (int w = 0; w < 16; ++w) {
            int idx = w * 256 + tid;
            int r = idx >> 4, c4 = (idx & 15) * 4;
            float4 v = *(const float4*)(Asrc[m] + abase + (long)r * 2048 + c4);
            ushort t4[4] = {f2bf(v.x), f2bf(v.y), f2bf(v.z), f2bf(v.w)};
            *(uint2*)&As[r][c4] = *(uint2*)t4;
        }
        // stage W: 1024 float4 chunks
#pragma unroll
        for (int w = 0; w < 4; ++w) {
            int idx = w * 256 + tid;
            int r = idx >> 4, c4 = (idx & 15) * 4;
            float4 v = *(const float4*)(Wsrc[m] + r * 64 + c4);
            ushort t4[4] = {f2bf(v.x), f2bf(v.y), f2bf(v.z), f2bf(v.w)};
            *(uint2*)&Ws[r][c4] = *(uint2*)t4;
        }
        __syncthreads();

        // MFMA: wave strip l in [wid*64, +64): 4 l-tiles x 4 e-tiles, K=64
        f32x4 acc[4][4];
#pragma unroll
        for (int lt = 0; lt < 4; ++lt)
#pragma unroll
            for (int et = 0; et < 4; ++et)
#pragma unroll
                for (int rg = 0; rg < 4; ++rg) acc[lt][et][rg] = 0.f;

#pragma unroll
        for (int ks = 0; ks < 2; ++ks) {
            bf16x8 a[4], bb[4];
#pragma unroll
            for (int lt = 0; lt < 4; ++lt)
                a[lt] = *(const bf16x8*)
                    &As[wid * 64 + lt * 16 + lr][ks * 32 + lk * 8];
#pragma unroll
            for (int et = 0; et < 4; ++et)
                bb[et] = *(const bf16x8*)
                    &Ws[et * 16 + lr][ks * 32 + lk * 8];
#pragma unroll
            for (int lt = 0; lt < 4; ++lt)
#pragma unroll
                for (int et = 0; et < 4; ++et)
                    acc[lt][et] = __builtin_amdgcn_mfma_f32_16x16x32_bf16(
                        a[lt], bb[et], acc[lt][et], 0, 0, 0);
        }

        // write: D col=e=et*16+lr, row=l=wid*64+lt*16+lk*4+rg
#pragma unroll
        for (int lt = 0; lt < 4; ++lt)
#pragma unroll
            for (int et = 0; et < 4; ++et)
#pragma unroll
                for (int rg = 0; rg < 4; ++rg) {
                    const int l = wid * 64 + lt * 16 + lk * 4 + rg;
                    const int e = et * 16 + lr;
                    Bdst[m][slice + (long)l * 64 + e] = f2bf(acc[lt][et][rg]);
                }
    }
}

// Fused stats+PV (frozen, r19): one block per nhs (all 256 q), 512 thr.
__global__ __launch_bounds__(512) void k_attn(
    const ushort* __restrict__ kB, const ushort* __restrict__ qB,
    const ushort* __restrict__ vB, const int* __restrict__ mask,
    ushort* __restrict__ Xb)
{
    __shared__ ushort Qs[256][72];    // 36,864 B  [q][k]
    __shared__ ushort Ks[32][72];     //  4,608 B  [l][k]
    __shared__ ushort vsT[64][40];    //  5,120 B  [d][l]
    __shared__ ushort Es[128][40];    // 10,240 B  [wave-q][l]
    __shared__ float Zl[256];         //  1,024 B
    __shared__ int mb16[16];
    const int nhs = blockIdx.x;
    const int n = nhs >> 5, h = (nhs >> 1) & 15, s = nhs & 1;
    const long slice = (long)nhs * 16384;
    const int tid = threadIdx.x;
    const int wid = tid >> 6, lane = tid & 63;
    const int lr = lane & 15, lk = lane >> 4;

#pragma unroll
    for (int w = 0; w < 4; ++w) {
        int idx = w * 512 + tid;
        int r = idx >> 3, c8 = (idx & 7) * 8;
        *(uint4*)&Qs[r][c8] = *(const uint4*)(qB + slice + r * 64 + c8);
    }
    const int mrow = n * 524288 + (h >> 3) * 262144 + (h & 7) * 32 + s * 16;
    if (tid < 16) mb16[tid] = mask[mrow + tid];
    if (tid < 256) Zl[tid] = 0.f;

    const float scale = 0.03125f;

    // ========== PHASE 1: Z accumulation ==========
#pragma unroll 1
    for (int sl = 0; sl < 8; ++sl) {
        __syncthreads();
        if (tid < 256) {
            int r = tid >> 3, c8 = (tid & 7) * 8;
            *(uint4*)&Ks[r][c8] =
                *(const uint4*)(kB + slice + (sl * 32 + r) * 64 + c8);
        }
        __syncthreads();

#pragma unroll
        for (int qt = 0; qt < 2; ++qt) {
            const int qb = wid * 32 + qt * 16;
            const bool live = (mb16[qb >> 4] != 0);
            if (!live) continue;
            bf16x8 a0 = *(const bf16x8*)&Qs[qb + lr][lk * 8];
            bf16x8 a1 = *(const bf16x8*)&Qs[qb + lr][32 + lk * 8];
#pragma unroll
            for (int lt = 0; lt < 2; ++lt) {
                f32x4 sacc;
#pragma unroll
                for (int rg = 0; rg < 4; ++rg) sacc[rg] = 0.f;
                bf16x8 b0 = *(const bf16x8*)&Ks[lt * 16 + lr][lk * 8];
                bf16x8 b1 = *(const bf16x8*)&Ks[lt * 16 + lr][32 + lk * 8];
                sacc = __builtin_amdgcn_mfma_f32_16x16x32_bf16(
                    a0, b0, sacc, 0, 0, 0);
                sacc = __builtin_amdgcn_mfma_f32_16x16x32_bf16(
                    a1, b1, sacc, 0, 0, 0);
                float zq = 0.f;
#pragma unroll
                for (int rg = 0; rg < 4; ++rg)
                    zq += __expf(sacc[rg] * scale);
                atomicAdd(&Zl[sl * 32 + lt * 16 + lr], zq);
            }
        }
    }

    __syncthreads();
    if (tid < 256) {
        float z = Zl[tid];
        Zl[tid] = (z > 0.f) ? 1.0f / z : 1.0f / 256.0f;
    }

    // ========== PHASE 2: att + PV ==========
    f32x4 acc0[4], acc1[4];
#pragma unroll
    for (int dt = 0; dt < 4; ++dt)
#pragma unroll
        for (int rg = 0; rg < 4; ++rg) { acc0[dt][rg] = 0.f; acc1[dt][rg] = 0.f; }

#pragma unroll 1
    for (int sl = 0; sl < 8; ++sl) {
        __syncthreads();
        if (tid < 256) {
            int r = tid >> 3, c8 = (tid & 7) * 8;
            *(uint4*)&Ks[r][c8] =
                *(const uint4*)(kB + slice + (sl * 32 + r) * 64 + c8);
        } else {
            int t = tid - 256;
            int l = t >> 3, d8 = (t & 7) * 8;
            uint4 vv = *(const uint4*)(vB + slice + (sl * 32 + l) * 64 + d8);
            ushort t8[8];
            *(uint4*)t8 = vv;
#pragma unroll
            for (int u = 0; u < 8; ++u) vsT[d8 + u][l] = t8[u];
        }
        __syncthreads();

#pragma unroll
        for (int qt = 0; qt < 2; ++qt) {
            const int qb = wid * 32 + qt * 16;
            const bool live = (mb16[qb >> 4] != 0);
            bf16x8 a0 = *(const bf16x8*)&Qs[qb + lr][lk * 8];
            bf16x8 a1 = *(const bf16x8*)&Qs[qb + lr][32 + lk * 8];
#pragma unroll
            for (int lt = 0; lt < 2; ++lt) {
                f32x4 sacc;
#pragma unroll
                for (int rg = 0; rg < 4; ++rg) sacc[rg] = 0.f;
                bf16x8 b0 = *(const bf16x8*)&Ks[lt * 16 + lr][lk * 8];
                bf16x8 b1 = *(const bf16x8*)&Ks[lt * 16 + lr][32 + lk * 8];
                sacc = __builtin_amdgcn_mfma_f32_16x16x32_bf16(
                    a0, b0, sacc, 0, 0, 0);
                sacc = __builtin_amdgcn_mfma_f32_16x16x32_bf16(
                    a1, b1, sacc, 0, 0, 0);
                const int l = lt * 16 + lr;
                const float iz = Zl[sl * 32 + l];
#pragma unroll
                for (int rg = 0; rg < 4; ++rg) {
                    float ev = live ? __expf(sacc[rg] * scale) * iz : 0.f;
                    Es[wid * 16 + lk * 4 + rg][l] = f2bf(ev);
                }
            }
            __builtin_amdgcn_s_waitcnt(0);  // lgkmcnt(0): wave-local Es
            bf16x8 aP = *(const bf16x8*)&Es[wid * 16 + lr][lk * 8];
            f32x4* accp = (qt == 0) ? acc0 : acc1;
#pragma unroll
            for (int dt = 0; dt < 4; ++dt) {
                bf16x8 bV = *(const bf16x8*)&vsT[dt * 16 + lr][lk * 8];
                accp[dt] = __builtin_amdgcn_mfma_f32_16x16x32_bf16(
                    aP, bV, accp[dt], 0, 0, 0);
            }
        }
    }

#pragma unroll
    for (int qt = 0; qt < 2; ++qt) {
        const f32x4* accp = (qt == 0) ? acc0 : acc1;
        const int qb = wid * 32 + qt * 16;
#pragma unroll
        for (int dt = 0; dt < 4; ++dt) {
#pragma unroll
            for (int rg = 0; rg < 4; ++rg) {
                const int q = qb + lk * 4 + rg;
                const int d = dt * 16 + lr;
                Xb[slice + (long)q * 64 + d] = f2bf(accp[dt][rg]);
            }
        }
    }
}

// MFMA k_wo (frozen, r17).
__global__ __launch_bounds__(512) void k_wo(
    const ushort* __restrict__ Xb, const ushort* __restrict__ Wb,
    const float* __restrict__ bo, float* __restrict__ out)
{
    __shared__ ushort Xs[128][72];
    __shared__ ushort Ws[128][72];
    const int b = blockIdx.x;
    const int by = b >> 3, bx = b & 7;
    const int r0 = by * 128, f0 = bx * 128;
    const int tid = threadIdx.x;
    const int wid = tid >> 6, lane = tid & 63;
    const int wr = wid >> 2, wc = wid & 3;
    const int lr = lane & 15, lk = lane >> 4;

    f32x4 acc[4][2];
#pragma unroll
    for (int rt = 0; rt < 4; ++rt)
#pragma unroll
        for (int ft = 0; ft < 2; ++ft)
#pragma unroll
            for (int rg = 0; rg < 4; ++rg) acc[rt][ft][rg] = 0.f;

    const int sr = tid >> 2, sc = (tid & 3) * 16;
    const int sR = r0 + sr;
    const int sn = sR >> 9, sq = (sR >> 1) & 255, ss2 = sR & 1;

#pragma unroll 1
    for (int eo = 0; eo < 1024; eo += 64) {
        const int hr = eo >> 7, sp = (eo >> 6) & 1;
        __syncthreads();
        {
            long xo = ((long)((sn * 16 + (ss2 * 8 + hr)) * 2 + sp)) * 16384 +
                      sq * 64 + sc;
            *(uint4*)&Xs[sr][sc] = *(const uint4*)(Xb + xo);
            *(uint4*)&Xs[sr][sc + 8] = *(const uint4*)(Xb + xo + 8);
            long wo = (long)(f0 + sr) * 1024 + eo + sc;
            *(uint4*)&Ws[sr][sc] = *(const uint4*)(Wb + wo);
            *(uint4*)&Ws[sr][sc + 8] = *(const uint4*)(Wb + wo + 8);
        }
        __syncthreads();

#pragma unroll
        for (int ks = 0; ks < 2; ++ks) {
            bf16x8 a[4], bb[2];
#pragma unroll
            for (int rt = 0; rt < 4; ++rt)
                a[rt] = *(const bf16x8*)
                    &Xs[wr * 64 + rt * 16 + lr][ks * 32 + lk * 8];
#pragma unroll
            for (int ft = 0; ft < 2; ++ft)
                bb[ft] = *(const bf16x8*)
                    &Ws[wc * 32 + ft * 16 + lr][ks * 32 + lk * 8];
#pragma unroll
            for (int rt = 0; rt < 4; ++rt)
#pragma unroll
                for (int ft = 0; ft < 2; ++ft)
                    acc[rt][ft] = __builtin_amdgcn_mfma_f32_16x16x32_bf16(
                        a[rt], bb[ft], acc[rt][ft], 0, 0, 0);
        }
    }

#pragma unroll
    for (int ft = 0; ft < 2; ++ft) {
        const int f = f0 + wc * 32 + ft * 16 + lr;
        const float bias = bo[f];
#pragma unroll
        for (int rt = 0; rt < 4; ++rt) {
#pragma unroll
            for (int rg = 0; rg < 4; ++rg) {
                const int r = r0 + wr * 64 + rt * 16 + lk * 4 + rg;
                out[(long)r * 1024 + f] = acc[rt][ft][rg] + bias;
            }
        }
    }
}

extern "C" void kernel_launch(void* const* d_in, const int* in_sizes, int n_in,
                              void* d_out, int out_size, void* d_ws,
                              size_t ws_size, hipStream_t stream)
{
    const float* vals = (const float*)d_in[0];
    const float* keys = (const float*)d_in[1];
    const float* qrys = (const float*)d_in[2];
    const int*   mask = (const int*)d_in[3];
    const float* Wv   = (const float*)d_in[4];
    const float* Wk   = (const float*)d_in[5];
    const float* Wq   = (const float*)d_in[6];
    const float* Wo   = (const float*)d_in[7];
    const float* bo   = (const float*)d_in[8];
    float* ws  = (float*)d_ws;
    ushort* kB = (ushort*)(ws);
    ushort* qB = (ushort*)(ws + 4194304);
    ushort* vB = (ushort*)(ws + 8388608);
    ushort* Xb = (ushort*)(ws + 12582912);
    ushort* Wb = (ushort*)(ws + 16777216);
    float* out = (float*)d_out;

    k_wot <<<1024, 256, 0, stream>>>(Wo, Wb);
    k_proj<<< 512, 256, 0, stream>>>(vals, keys, qrys, Wv, Wk, Wq, kB, qB, vB);
    k_attn<<< 512, 512, 0, stream>>>(kB, qB, vB, mask, Xb);
    k_wo  <<< 512, 512, 0, stream>>>(Xb, Wb, bo, out);
}

// Round 21
// 104.316 us; speedup vs baseline: 8.9265x; 1.2466x over previous
//
#include <hip/hip_runtime.h>

// EntailmentSelfAttention: N=16, L=256, S=2, H=16, D=64, E=1024
//
// Pipeline (4 kernels):
//   K0 k_wot  : Wb[f][e'] = bf16(Wo[f][perm(e')]) (frozen, r17).
//   K1 k_proj : bf16 MFMA projections (frozen, r20).
//   K2 k_attn : fused stats+PV MFMA, v2. r20 counters: 64us, MfmaUtil 6%,
//               Occ 31% -> latency-bound. Fixes this round:
//               (a) Qs LDS (36.9KB) DELETED - each wave only reads its own
//                   32-q strip -> Q frags live in 16 VGPRs (aq[2][2]).
//               (b) Zl atomicAdd storm removed: zlt[2] regs per slab,
//                   shfl_xor(16/32) reduce over lk, single conflict-free
//                   atomicAdd from lk==0 lanes (16x fewer lane-ops).
//               (c) Es/vsT stride 40 -> 44 (22r mod 32 full-period ->
//                   conflict-free row starts).
//               LDS 58.4 -> 22.6 KB -> occupancy ~24+ waves/CU.
//   K3 k_wo   : bf16 MFMA GEMM (frozen, r17).
//
// ws layout (f32-elem offsets): kB @0, qB @4194304, vB @8388608,
//   Xb @12582912, Wb @16777216.

typedef __attribute__((ext_vector_type(8))) short bf16x8;
typedef __attribute__((ext_vector_type(4))) float f32x4;

__device__ inline ushort f2bf(float x) {
    uint u = __float_as_uint(x);
    u += 0x7FFFu + ((u >> 16) & 1u);
    return (ushort)(u >> 16);
}

__global__ __launch_bounds__(256) void k_wot(
    const float* __restrict__ Wo, ushort* __restrict__ Wb)
{
    const int f = blockIdx.x;          // 0..1023
    const int e4 = threadIdx.x * 4;    // e' base (d%4==0, fixed hr/sp)
    const int hr = e4 >> 7, sp = (e4 >> 6) & 1, d = e4 & 63;
    const float* wrow = Wo + (long)f * 1024 + hr * 128 + 2 * d + sp;
    ushort o[4] = {f2bf(wrow[0]), f2bf(wrow[2]), f2bf(wrow[4]), f2bf(wrow[6])};
    *(uint2*)(Wb + (long)f * 1024 + e4) = *(uint2*)o;
}

// MFMA projections (frozen, r20): block = (n,h,s) slice; 256 thr = 4 waves.
__global__ __launch_bounds__(256) void k_proj(
    const float* __restrict__ Av, const float* __restrict__ Ak,
    const float* __restrict__ Aq, const float* __restrict__ Wv,
    const float* __restrict__ Wk, const float* __restrict__ Wq,
    ushort* __restrict__ kB, ushort* __restrict__ qB,
    ushort* __restrict__ vB)
{
    __shared__ ushort As[256][72];   // 36,864 B  [l][d]
    __shared__ ushort Ws[64][72];    //  9,216 B  [e][d]
    const int b = blockIdx.x;
    const int n = b >> 5, h = (b >> 1) & 15, s = b & 1;
    const float* Asrc[3] = {Av, Ak, Aq};
    const float* Wsrc[3] = {Wv, Wk, Wq};
    const int tid = threadIdx.x;
    const int wid = tid >> 6, lane = tid & 63;
    const int lr = lane & 15, lk = lane >> 4;

    const long abase = (long)n * 524288 + s * 1024 + h * 64;
    const long slice = ((long)((n * 16 + h) * 2 + s)) * 16384;
    ushort* Bdst[3] = {vB, kB, qB};

#pragma unroll 1
    for (int m = 0; m < 3; ++m) {
        __syncthreads();
#pragma unroll
        for (int w = 0; w < 16; ++w) {
            int idx = w * 256 + tid;
            int r = idx >> 4, c4 = (idx & 15) * 4;
            float4 v = *(const float4*)(Asrc[m] + abase + (long)r * 2048 + c4);
            ushort t4[4] = {f2bf(v.x), f2bf(v.y), f2bf(v.z), f2bf(v.w)};
            *(uint2*)&As[r][c4] = *(uint2*)t4;
        }
#pragma unroll
        for (int w = 0; w < 4; ++w) {
            int idx = w * 256 + tid;
            int r = idx >> 4, c4 = (idx & 15) * 4;
            float4 v = *(const float4*)(Wsrc[m] + r * 64 + c4);
            ushort t4[4] = {f2bf(v.x), f2bf(v.y), f2bf(v.z), f2bf(v.w)};
            *(uint2*)&Ws[r][c4] = *(uint2*)t4;
        }
        __syncthreads();

        f32x4 acc[4][4];
#pragma unroll
        for (int lt = 0; lt < 4; ++lt)
#pragma unroll
            for (int et = 0; et < 4; ++et)
#pragma unroll
                for (int rg = 0; rg < 4; ++rg) acc[lt][et][rg] = 0.f;

#pragma unroll
        for (int ks = 0; ks < 2; ++ks) {
            bf16x8 a[4], bb[4];
#pragma unroll
            for (int lt = 0; lt < 4; ++lt)
                a[lt] = *(const bf16x8*)
                    &As[wid * 64 + lt * 16 + lr][ks * 32 + lk * 8];
#pragma unroll
            for (int et = 0; et < 4; ++et)
                bb[et] = *(const bf16x8*)
                    &Ws[et * 16 + lr][ks * 32 + lk * 8];
#pragma unroll
            for (int lt = 0; lt < 4; ++lt)
#pragma unroll
                for (int et = 0; et < 4; ++et)
                    acc[lt][et] = __builtin_amdgcn_mfma_f32_16x16x32_bf16(
                        a[lt], bb[et], acc[lt][et], 0, 0, 0);
        }

#pragma unroll
        for (int lt = 0; lt < 4; ++lt)
#pragma unroll
            for (int et = 0; et < 4; ++et)
#pragma unroll
                for (int rg = 0; rg < 4; ++rg) {
                    const int l = wid * 64 + lt * 16 + lk * 4 + rg;
                    const int e = et * 16 + lr;
                    Bdst[m][slice + (long)l * 64 + e] = f2bf(acc[lt][et][rg]);
                }
    }
}

// Fused stats+PV v2: one block per nhs (all 256 q), 512 thr = 8 waves;
// wave owns q-strip [wid*32,+32) as two 16-q tiles (Q frags in registers).
__global__ __launch_bounds__(512) void k_attn(
    const ushort* __restrict__ kB, const ushort* __restrict__ qB,
    const ushort* __restrict__ vB, const int* __restrict__ mask,
    ushort* __restrict__ Xb)
{
    __shared__ ushort Ks[32][72];     //  4,608 B  [l][k]
    __shared__ ushort vsT[64][44];    //  5,632 B  [d][l]
    __shared__ ushort Es[128][44];    // 11,264 B  [wave-q][l]
    __shared__ float Zl[256];         //  1,024 B
    __shared__ int mb16[16];
    const int nhs = blockIdx.x;
    const int n = nhs >> 5, h = (nhs >> 1) & 15, s = nhs & 1;
    const long slice = (long)nhs * 16384;
    const int tid = threadIdx.x;
    const int wid = tid >> 6, lane = tid & 63;
    const int lr = lane & 15, lk = lane >> 4;

    // Q fragments in registers: wave's two 16-q tiles, K=64 (2 ks-halves)
    bf16x8 aq[2][2];
#pragma unroll
    for (int qt = 0; qt < 2; ++qt) {
        const int qb = wid * 32 + qt * 16;
        aq[qt][0] = *(const bf16x8*)(qB + slice + (qb + lr) * 64 + lk * 8);
        aq[qt][1] = *(const bf16x8*)(qB + slice + (qb + lr) * 64 + 32 + lk * 8);
    }
    const int mrow = n * 524288 + (h >> 3) * 262144 + (h & 7) * 32 + s * 16;
    if (tid < 16) mb16[tid] = mask[mrow + tid];
    if (tid < 256) Zl[tid] = 0.f;

    const float scale = 0.03125f;

    // ========== PHASE 1: Z accumulation (register partials) ==========
#pragma unroll 1
    for (int sl = 0; sl < 8; ++sl) {
        __syncthreads();   // Zl/mb16 ready (sl=0) / prev Ks reads done
        if (tid < 256) {
            int r = tid >> 3, c8 = (tid & 7) * 8;
            *(uint4*)&Ks[r][c8] =
                *(const uint4*)(kB + slice + (sl * 32 + r) * 64 + c8);
        }
        __syncthreads();

        float zlt[2] = {0.f, 0.f};
#pragma unroll
        for (int qt = 0; qt < 2; ++qt) {
            const int qb = wid * 32 + qt * 16;
            if (mb16[qb >> 4] == 0) continue;  // masked q: exp -> 0
#pragma unroll
            for (int lt = 0; lt < 2; ++lt) {
                f32x4 sacc;
#pragma unroll
                for (int rg = 0; rg < 4; ++rg) sacc[rg] = 0.f;
                bf16x8 b0 = *(const bf16x8*)&Ks[lt * 16 + lr][lk * 8];
                bf16x8 b1 = *(const bf16x8*)&Ks[lt * 16 + lr][32 + lk * 8];
                sacc = __builtin_amdgcn_mfma_f32_16x16x32_bf16(
                    aq[qt][0], b0, sacc, 0, 0, 0);
                sacc = __builtin_amdgcn_mfma_f32_16x16x32_bf16(
                    aq[qt][1], b1, sacc, 0, 0, 0);
                // D: col=l=lt*16+lr, row=q=qb+lk*4+rg
#pragma unroll
                for (int rg = 0; rg < 4; ++rg)
                    zlt[lt] += __expf(sacc[rg] * scale);
            }
        }
        // reduce over lk (lanes xor 16, 32), one clean atomic per lt
#pragma unroll
        for (int lt = 0; lt < 2; ++lt) {
            float v = zlt[lt];
            v += __shfl_xor(v, 16);
            v += __shfl_xor(v, 32);
            if (lk == 0)
                atomicAdd(&Zl[sl * 32 + lt * 16 + lr], v);
        }
    }

    __syncthreads();
    if (tid < 256) {
        float z = Zl[tid];
        Zl[tid] = (z > 0.f) ? 1.0f / z : 1.0f / 256.0f;
    }

    // ========== PHASE 2: att + PV ==========
    f32x4 acc0[4], acc1[4];
#pragma unroll
    for (int dt = 0; dt < 4; ++dt)
#pragma unroll
        for (int rg = 0; rg < 4; ++rg) { acc0[dt][rg] = 0.f; acc1[dt][rg] = 0.f; }

#pragma unroll 1
    for (int sl = 0; sl < 8; ++sl) {
        __syncthreads();   // Zl ready (sl=0) / prev Ks,vsT,Es reads done
        if (tid < 256) {
            int r = tid >> 3, c8 = (tid & 7) * 8;
            *(uint4*)&Ks[r][c8] =
                *(const uint4*)(kB + slice + (sl * 32 + r) * 64 + c8);
        } else {
            int t = tid - 256;
            int l = t >> 3, d8 = (t & 7) * 8;
            uint4 vv = *(const uint4*)(vB + slice + (sl * 32 + l) * 64 + d8);
            ushort t8[8];
            *(uint4*)t8 = vv;
#pragma unroll
            for (int u = 0; u < 8; ++u) vsT[d8 + u][l] = t8[u];
        }
        __syncthreads();

#pragma unroll
        for (int qt = 0; qt < 2; ++qt) {
            const int qb = wid * 32 + qt * 16;
            const bool live = (mb16[qb >> 4] != 0);
#pragma unroll
            for (int lt = 0; lt < 2; ++lt) {
                f32x4 sacc;
#pragma unroll
                for (int rg = 0; rg < 4; ++rg) sacc[rg] = 0.f;
                bf16x8 b0 = *(const bf16x8*)&Ks[lt * 16 + lr][lk * 8];
                bf16x8 b1 = *(const bf16x8*)&Ks[lt * 16 + lr][32 + lk * 8];
                sacc = __builtin_amdgcn_mfma_f32_16x16x32_bf16(
                    aq[qt][0], b0, sacc, 0, 0, 0);
                sacc = __builtin_amdgcn_mfma_f32_16x16x32_bf16(
                    aq[qt][1], b1, sacc, 0, 0, 0);
                const int l = lt * 16 + lr;
                const float iz = Zl[sl * 32 + l];
#pragma unroll
                for (int rg = 0; rg < 4; ++rg) {
                    float ev = live ? __expf(sacc[rg] * scale) * iz : 0.f;
                    Es[wid * 16 + lk * 4 + rg][l] = f2bf(ev);
                }
            }
            __builtin_amdgcn_s_waitcnt(0);  // lgkmcnt(0): wave-local Es
            bf16x8 aP = *(const bf16x8*)&Es[wid * 16 + lr][lk * 8];
            f32x4* accp = (qt == 0) ? acc0 : acc1;
#pragma unroll
            for (int dt = 0; dt < 4; ++dt) {
                bf16x8 bV = *(const bf16x8*)&vsT[dt * 16 + lr][lk * 8];
                accp[dt] = __builtin_amdgcn_mfma_f32_16x16x32_bf16(
                    aP, bV, accp[dt], 0, 0, 0);
            }
        }
    }

    // epilogue: D col=d, row=q-local -> Xb[nhs][q][d]
#pragma unroll
    for (int qt = 0; qt < 2; ++qt) {
        const f32x4* accp = (qt == 0) ? acc0 : acc1;
        const int qb = wid * 32 + qt * 16;
#pragma unroll
        for (int dt = 0; dt < 4; ++dt) {
#pragma unroll
            for (int rg = 0; rg < 4; ++rg) {
                const int q = qb + lk * 4 + rg;
                const int d = dt * 16 + lr;
                Xb[slice + (long)q * 64 + d] = f2bf(accp[dt][rg]);
            }
        }
    }
}

// MFMA k_wo (frozen, r17).
__global__ __launch_bounds__(512) void k_wo(
    const ushort* __restrict__ Xb, const ushort* __restrict__ Wb,
    const float* __restrict__ bo, float* __restrict__ out)
{
    __shared__ ushort Xs[128][72];
    __shared__ ushort Ws[128][72];
    const int b = blockIdx.x;
    const int by = b >> 3, bx = b & 7;
    const int r0 = by * 128, f0 = bx * 128;
    const int tid = threadIdx.x;
    const int wid = tid >> 6, lane = tid & 63;
    const int wr = wid >> 2, wc = wid & 3;
    const int lr = lane & 15, lk = lane >> 4;

    f32x4 acc[4][2];
#pragma unroll
    for (int rt = 0; rt < 4; ++rt)
#pragma unroll
        for (int ft = 0; ft < 2; ++ft)
#pragma unroll
            for (int rg = 0; rg < 4; ++rg) acc[rt][ft][rg] = 0.f;

    const int sr = tid >> 2, sc = (tid & 3) * 16;
    const int sR = r0 + sr;
    const int sn = sR >> 9, sq = (sR >> 1) & 255, ss2 = sR & 1;

#pragma unroll 1
    for (int eo = 0; eo < 1024; eo += 64) {
        const int hr = eo >> 7, sp = (eo >> 6) & 1;
        __syncthreads();
        {
            long xo = ((long)((sn * 16 + (ss2 * 8 + hr)) * 2 + sp)) * 16384 +
                      sq * 64 + sc;
            *(uint4*)&Xs[sr][sc] = *(const uint4*)(Xb + xo);
            *(uint4*)&Xs[sr][sc + 8] = *(const uint4*)(Xb + xo + 8);
            long wo = (long)(f0 + sr) * 1024 + eo + sc;
            *(uint4*)&Ws[sr][sc] = *(const uint4*)(Wb + wo);
            *(uint4*)&Ws[sr][sc + 8] = *(const uint4*)(Wb + wo + 8);
        }
        __syncthreads();

#pragma unroll
        for (int ks = 0; ks < 2; ++ks) {
            bf16x8 a[4], bb[2];
#pragma unroll
            for (int rt = 0; rt < 4; ++rt)
                a[rt] = *(const bf16x8*)
                    &Xs[wr * 64 + rt * 16 + lr][ks * 32 + lk * 8];
#pragma unroll
            for (int ft = 0; ft < 2; ++ft)
                bb[ft] = *(const bf16x8*)
                    &Ws[wc * 32 + ft * 16 + lr][ks * 32 + lk * 8];
#pragma unroll
            for (int rt = 0; rt < 4; ++rt)
#pragma unroll
                for (int ft = 0; ft < 2; ++ft)
                    acc[rt][ft] = __builtin_amdgcn_mfma_f32_16x16x32_bf16(
                        a[rt], bb[ft], acc[rt][ft], 0, 0, 0);
        }
    }

#pragma unroll
    for (int ft = 0; ft < 2; ++ft) {
        const int f = f0 + wc * 32 + ft * 16 + lr;
        const float bias = bo[f];
#pragma unroll
        for (int rt = 0; rt < 4; ++rt) {
#pragma unroll
            for (int rg = 0; rg < 4; ++rg) {
                const int r = r0 + wr * 64 + rt * 16 + lk * 4 + rg;
                out[(long)r * 1024 + f] = acc[rt][ft][rg] + bias;
            }
        }
    }
}

extern "C" void kernel_launch(void* const* d_in, const int* in_sizes, int n_in,
                              void* d_out, int out_size, void* d_ws,
                              size_t ws_size, hipStream_t stream)
{
    const float* vals = (const float*)d_in[0];
    const float* keys = (const float*)d_in[1];
    const float* qrys = (const float*)d_in[2];
    const int*   mask = (const int*)d_in[3];
    const float* Wv   = (const float*)d_in[4];
    const float* Wk   = (const float*)d_in[5];
    const float* Wq   = (const float*)d_in[6];
    const float* Wo   = (const float*)d_in[7];
    const float* bo   = (const float*)d_in[8];
    float* ws  = (float*)d_ws;
    ushort* kB = (ushort*)(ws);
    ushort* qB = (ushort*)(ws + 4194304);
    ushort* vB = (ushort*)(ws + 8388608);
    ushort* Xb = (ushort*)(ws + 12582912);
    ushort* Wb = (ushort*)(ws + 16777216);
    float* out = (float*)d_out;

    k_wot <<<1024, 256, 0, stream>>>(Wo, Wb);
    k_proj<<< 512, 256, 0, stream>>>(vals, keys, qrys, Wv, Wk, Wq, kB, qB, vB);
    k_attn<<< 512, 512, 0, stream>>>(kB, qB, vB, mask, Xb);
    k_wo  <<< 512, 512, 0, stream>>>(Xb, Wb, bo, out);
}

// Round 22
// 97.624 us; speedup vs baseline: 9.5384x; 1.0685x over previous
//
#include <hip/hip_runtime.h>

// EntailmentSelfAttention: N=16, L=256, S=2, H=16, D=64, E=1024
//
// Pipeline (4 kernels):
//   K0 k_wot  : Wb[f][e'] = bf16(Wo[f][perm(e')]) (frozen, r17).
//   K1 k_proj : v2 barrier-free streaming MFMA. r21: 54us, MfmaUtil 2%,
//               Occ 19% - 6 barrier drains + 46KB LDS. Insight: MFMA
//               B-op frag (col=lane&15, k=lk*8+j) maps DIRECTLY onto
//               A's row-major global layout -> A loads global->reg,
//               no staging. Operands swapped (A-op = W from LDS, B-op =
//               A-slice) so D is col=l,row=e -> uint2 vector stores.
//               W (3 tensors, 27.6KB bf16) staged once, ONE barrier,
//               then pure stream: 48 indep float4 loads + MFMA + uint2
//               stores per thread. ~60 VGPR, 5 blocks/CU, 20 waves/CU.
//   K2 k_attn : fused stats+PV MFMA v2 (frozen, r21).
//   K3 k_wo   : bf16 MFMA GEMM (frozen, r17).
//
// ws layout (f32-elem offsets): kB @0, qB @4194304, vB @8388608,
//   Xb @12582912, Wb @16777216.

typedef __attribute__((ext_vector_type(8))) short bf16x8;
typedef __attribute__((ext_vector_type(4))) float f32x4;

__device__ inline ushort f2bf(float x) {
    uint u = __float_as_uint(x);
    u += 0x7FFFu + ((u >> 16) & 1u);
    return (ushort)(u >> 16);
}

__global__ __launch_bounds__(256) void k_wot(
    const float* __restrict__ Wo, ushort* __restrict__ Wb)
{
    const int f = blockIdx.x;          // 0..1023
    const int e4 = threadIdx.x * 4;    // e' base (d%4==0, fixed hr/sp)
    const int hr = e4 >> 7, sp = (e4 >> 6) & 1, d = e4 & 63;
    const float* wrow = Wo + (long)f * 1024 + hr * 128 + 2 * d + sp;
    ushort o[4] = {f2bf(wrow[0]), f2bf(wrow[2]), f2bf(wrow[4]), f2bf(wrow[6])};
    *(uint2*)(Wb + (long)f * 1024 + e4) = *(uint2*)o;
}

// Streaming MFMA projections v2: block = (n,h,s) slice; 256 thr = 4 waves;
// wave owns l-strip [wid*64,+64). A-op = W (LDS), B-op = A rows (global
// direct). D col=l,row=e -> uint2 stores. One barrier total.
__global__ __launch_bounds__(256) void k_proj(
    const float* __restrict__ Av, const float* __restrict__ Ak,
    const float* __restrict__ Aq, const float* __restrict__ Wv,
    const float* __restrict__ Wk, const float* __restrict__ Wq,
    ushort* __restrict__ kB, ushort* __restrict__ qB,
    ushort* __restrict__ vB)
{
    __shared__ ushort Wsb[3][64][72];   // 27,648 B  [m][e][d]
    const int b = blockIdx.x;
    const int n = b >> 5, h = (b >> 1) & 15, s = b & 1;
    const float* Asrc[3] = {Av, Ak, Aq};
    const float* Wsrc[3] = {Wv, Wk, Wq};
    const int tid = threadIdx.x;
    const int wid = tid >> 6, lane = tid & 63;
    const int lr = lane & 15, lk = lane >> 4;

    const long abase = (long)n * 524288 + s * 1024 + h * 64;
    const long slice = ((long)((n * 16 + h) * 2 + s)) * 16384;
    ushort* Bdst[3] = {vB, kB, qB};

    // stage all 3 W matrices once (f32 -> bf16)
#pragma unroll
    for (int m = 0; m < 3; ++m)
#pragma unroll
        for (int w = 0; w < 4; ++w) {
            int idx = w * 256 + tid;
            int r = idx >> 4, c4 = (idx & 15) * 4;
            float4 v = *(const float4*)(Wsrc[m] + r * 64 + c4);
            ushort t4[4] = {f2bf(v.x), f2bf(v.y), f2bf(v.z), f2bf(v.w)};
            *(uint2*)&Wsb[m][r][c4] = *(uint2*)t4;
        }
    __syncthreads();   // the only barrier

    const int l0 = wid * 64;
#pragma unroll 1
    for (int m = 0; m < 3; ++m) {
        const float* A = Asrc[m];
        ushort* B = Bdst[m];
#pragma unroll
        for (int lt = 0; lt < 4; ++lt) {
            const int lrow = l0 + lt * 16 + lr;
            const float* arow = A + abase + (long)lrow * 2048;
            // B-op frags direct from global (col=l -> lane's own row)
            bf16x8 bfrag[2];
#pragma unroll
            for (int ks = 0; ks < 2; ++ks) {
                float4 v0 = *(const float4*)(arow + ks * 32 + lk * 8);
                float4 v1 = *(const float4*)(arow + ks * 32 + lk * 8 + 4);
                ushort t8[8] = {f2bf(v0.x), f2bf(v0.y), f2bf(v0.z), f2bf(v0.w),
                                f2bf(v1.x), f2bf(v1.y), f2bf(v1.z), f2bf(v1.w)};
                bfrag[ks] = *(bf16x8*)t8;
            }
#pragma unroll
            for (int et = 0; et < 4; ++et) {
                f32x4 acc;
#pragma unroll
                for (int rg = 0; rg < 4; ++rg) acc[rg] = 0.f;
#pragma unroll
                for (int ks = 0; ks < 2; ++ks) {
                    bf16x8 wfrag = *(const bf16x8*)
                        &Wsb[m][et * 16 + lr][ks * 32 + lk * 8];
                    acc = __builtin_amdgcn_mfma_f32_16x16x32_bf16(
                        wfrag, bfrag[ks], acc, 0, 0, 0);
                }
                // D: col=l=lrow (lane's lr), row=e=et*16+lk*4+rg
                ushort t4[4] = {f2bf(acc[0]), f2bf(acc[1]),
                                f2bf(acc[2]), f2bf(acc[3])};
                *(uint2*)(B + slice + (long)lrow * 64 + et * 16 + lk * 4) =
                    *(uint2*)t4;
            }
        }
    }
}

// Fused stats+PV v2 (frozen, r21): one block per nhs, 512 thr = 8 waves.
__global__ __launch_bounds__(512) void k_attn(
    const ushort* __restrict__ kB, const ushort* __restrict__ qB,
    const ushort* __restrict__ vB, const int* __restrict__ mask,
    ushort* __restrict__ Xb)
{
    __shared__ ushort Ks[32][72];     //  4,608 B  [l][k]
    __shared__ ushort vsT[64][44];    //  5,632 B  [d][l]
    __shared__ ushort Es[128][44];    // 11,264 B  [wave-q][l]
    __shared__ float Zl[256];         //  1,024 B
    __shared__ int mb16[16];
    const int nhs = blockIdx.x;
    const int n = nhs >> 5, h = (nhs >> 1) & 15, s = nhs & 1;
    const long slice = (long)nhs * 16384;
    const int tid = threadIdx.x;
    const int wid = tid >> 6, lane = tid & 63;
    const int lr = lane & 15, lk = lane >> 4;

    bf16x8 aq[2][2];
#pragma unroll
    for (int qt = 0; qt < 2; ++qt) {
        const int qb = wid * 32 + qt * 16;
        aq[qt][0] = *(const bf16x8*)(qB + slice + (qb + lr) * 64 + lk * 8);
        aq[qt][1] = *(const bf16x8*)(qB + slice + (qb + lr) * 64 + 32 + lk * 8);
    }
    const int mrow = n * 524288 + (h >> 3) * 262144 + (h & 7) * 32 + s * 16;
    if (tid < 16) mb16[tid] = mask[mrow + tid];
    if (tid < 256) Zl[tid] = 0.f;

    const float scale = 0.03125f;

    // ========== PHASE 1: Z accumulation ==========
#pragma unroll 1
    for (int sl = 0; sl < 8; ++sl) {
        __syncthreads();
        if (tid < 256) {
            int r = tid >> 3, c8 = (tid & 7) * 8;
            *(uint4*)&Ks[r][c8] =
                *(const uint4*)(kB + slice + (sl * 32 + r) * 64 + c8);
        }
        __syncthreads();

        float zlt[2] = {0.f, 0.f};
#pragma unroll
        for (int qt = 0; qt < 2; ++qt) {
            const int qb = wid * 32 + qt * 16;
            if (mb16[qb >> 4] == 0) continue;
#pragma unroll
            for (int lt = 0; lt < 2; ++lt) {
                f32x4 sacc;
#pragma unroll
                for (int rg = 0; rg < 4; ++rg) sacc[rg] = 0.f;
                bf16x8 b0 = *(const bf16x8*)&Ks[lt * 16 + lr][lk * 8];
                bf16x8 b1 = *(const bf16x8*)&Ks[lt * 16 + lr][32 + lk * 8];
                sacc = __builtin_amdgcn_mfma_f32_16x16x32_bf16(
                    aq[qt][0], b0, sacc, 0, 0, 0);
                sacc = __builtin_amdgcn_mfma_f32_16x16x32_bf16(
                    aq[qt][1], b1, sacc, 0, 0, 0);
#pragma unroll
                for (int rg = 0; rg < 4; ++rg)
                    zlt[lt] += __expf(sacc[rg] * scale);
            }
        }
#pragma unroll
        for (int lt = 0; lt < 2; ++lt) {
            float v = zlt[lt];
            v += __shfl_xor(v, 16);
            v += __shfl_xor(v, 32);
            if (lk == 0)
                atomicAdd(&Zl[sl * 32 + lt * 16 + lr], v);
        }
    }

    __syncthreads();
    if (tid < 256) {
        float z = Zl[tid];
        Zl[tid] = (z > 0.f) ? 1.0f / z : 1.0f / 256.0f;
    }

    // ========== PHASE 2: att + PV ==========
    f32x4 acc0[4], acc1[4];
#pragma unroll
    for (int dt = 0; dt < 4; ++dt)
#pragma unroll
        for (int rg = 0; rg < 4; ++rg) { acc0[dt][rg] = 0.f; acc1[dt][rg] = 0.f; }

#pragma unroll 1
    for (int sl = 0; sl < 8; ++sl) {
        __syncthreads();
        if (tid < 256) {
            int r = tid >> 3, c8 = (tid & 7) * 8;
            *(uint4*)&Ks[r][c8] =
                *(const uint4*)(kB + slice + (sl * 32 + r) * 64 + c8);
        } else {
            int t = tid - 256;
            int l = t >> 3, d8 = (t & 7) * 8;
            uint4 vv = *(const uint4*)(vB + slice + (sl * 32 + l) * 64 + d8);
            ushort t8[8];
            *(uint4*)t8 = vv;
#pragma unroll
            for (int u = 0; u < 8; ++u) vsT[d8 + u][l] = t8[u];
        }
        __syncthreads();

#pragma unroll
        for (int qt = 0; qt < 2; ++qt) {
            const int qb = wid * 32 + qt * 16;
            const bool live = (mb16[qb >> 4] != 0);
#pragma unroll
            for (int lt = 0; lt < 2; ++lt) {
                f32x4 sacc;
#pragma unroll
                for (int rg = 0; rg < 4; ++rg) sacc[rg] = 0.f;
                bf16x8 b0 = *(const bf16x8*)&Ks[lt * 16 + lr][lk * 8];
                bf16x8 b1 = *(const bf16x8*)&Ks[lt * 16 + lr][32 + lk * 8];
                sacc = __builtin_amdgcn_mfma_f32_16x16x32_bf16(
                    aq[qt][0], b0, sacc, 0, 0, 0);
                sacc = __builtin_amdgcn_mfma_f32_16x16x32_bf16(
                    aq[qt][1], b1, sacc, 0, 0, 0);
                const int l = lt * 16 + lr;
                const float iz = Zl[sl * 32 + l];
#pragma unroll
                for (int rg = 0; rg < 4; ++rg) {
                    float ev = live ? __expf(sacc[rg] * scale) * iz : 0.f;
                    Es[wid * 16 + lk * 4 + rg][l] = f2bf(ev);
                }
            }
            __builtin_amdgcn_s_waitcnt(0);  // lgkmcnt(0): wave-local Es
            bf16x8 aP = *(const bf16x8*)&Es[wid * 16 + lr][lk * 8];
            f32x4* accp = (qt == 0) ? acc0 : acc1;
#pragma unroll
            for (int dt = 0; dt < 4; ++dt) {
                bf16x8 bV = *(const bf16x8*)&vsT[dt * 16 + lr][lk * 8];
                accp[dt] = __builtin_amdgcn_mfma_f32_16x16x32_bf16(
                    aP, bV, accp[dt], 0, 0, 0);
            }
        }
    }

#pragma unroll
    for (int qt = 0; qt < 2; ++qt) {
        const f32x4* accp = (qt == 0) ? acc0 : acc1;
        const int qb = wid * 32 + qt * 16;
#pragma unroll
        for (int dt = 0; dt < 4; ++dt) {
#pragma unroll
            for (int rg = 0; rg < 4; ++rg) {
                const int q = qb + lk * 4 + rg;
                const int d = dt * 16 + lr;
                Xb[slice + (long)q * 64 + d] = f2bf(accp[dt][rg]);
            }
        }
    }
}

// MFMA k_wo (frozen, r17).
__global__ __launch_bounds__(512) void k_wo(
    const ushort* __restrict__ Xb, const ushort* __restrict__ Wb,
    const float* __restrict__ bo, float* __restrict__ out)
{
    __shared__ ushort Xs[128][72];
    __shared__ ushort Ws[128][72];
    const int b = blockIdx.x;
    const int by = b >> 3, bx = b & 7;
    const int r0 = by * 128, f0 = bx * 128;
    const int tid = threadIdx.x;
    const int wid = tid >> 6, lane = tid & 63;
    const int wr = wid >> 2, wc = wid & 3;
    const int lr = lane & 15, lk = lane >> 4;

    f32x4 acc[4][2];
#pragma unroll
    for (int rt = 0; rt < 4; ++rt)
#pragma unroll
        for (int ft = 0; ft < 2; ++ft)
#pragma unroll
            for (int rg = 0; rg < 4; ++rg) acc[rt][ft][rg] = 0.f;

    const int sr = tid >> 2, sc = (tid & 3) * 16;
    const int sR = r0 + sr;
    const int sn = sR >> 9, sq = (sR >> 1) & 255, ss2 = sR & 1;

#pragma unroll 1
    for (int eo = 0; eo < 1024; eo += 64) {
        const int hr = eo >> 7, sp = (eo >> 6) & 1;
        __syncthreads();
        {
            long xo = ((long)((sn * 16 + (ss2 * 8 + hr)) * 2 + sp)) * 16384 +
                      sq * 64 + sc;
            *(uint4*)&Xs[sr][sc] = *(const uint4*)(Xb + xo);
            *(uint4*)&Xs[sr][sc + 8] = *(const uint4*)(Xb + xo + 8);
            long wo = (long)(f0 + sr) * 1024 + eo + sc;
            *(uint4*)&Ws[sr][sc] = *(const uint4*)(Wb + wo);
            *(uint4*)&Ws[sr][sc + 8] = *(const uint4*)(Wb + wo + 8);
        }
        __syncthreads();

#pragma unroll
        for (int ks = 0; ks < 2; ++ks) {
            bf16x8 a[4], bb[2];
#pragma unroll
            for (int rt = 0; rt < 4; ++rt)
                a[rt] = *(const bf16x8*)
                    &Xs[wr * 64 + rt * 16 + lr][ks * 32 + lk * 8];
#pragma unroll
            for (int ft = 0; ft < 2; ++ft)
                bb[ft] = *(const bf16x8*)
                    &Ws[wc * 32 + ft * 16 + lr][ks * 32 + lk * 8];
#pragma unroll
            for (int rt = 0; rt < 4; ++rt)
#pragma unroll
                for (int ft = 0; ft < 2; ++ft)
                    acc[rt][ft] = __builtin_amdgcn_mfma_f32_16x16x32_bf16(
                        a[rt], bb[ft], acc[rt][ft], 0, 0, 0);
        }
    }

#pragma unroll
    for (int ft = 0; ft < 2; ++ft) {
        const int f = f0 + wc * 32 + ft * 16 + lr;
        const float bias = bo[f];
#pragma unroll
        for (int rt = 0; rt < 4; ++rt) {
#pragma unroll
            for (int rg = 0; rg < 4; ++rg) {
                const int r = r0 + wr * 64 + rt * 16 + lk * 4 + rg;
                out[(long)r * 1024 + f] = acc[rt][ft][rg] + bias;
            }
        }
    }
}

extern "C" void kernel_launch(void* const* d_in, const int* in_sizes, int n_in,
                              void* d_out, int out_size, void* d_ws,
                              size_t ws_size, hipStream_t stream)
{
    const float* vals = (const float*)d_in[0];
    const float* keys = (const float*)d_in[1];
    const float* qrys = (const float*)d_in[2];
    const int*   mask = (const int*)d_in[3];
    const float* Wv   = (const float*)d_in[4];
    const float* Wk   = (const float*)d_in[5];
    const float* Wq   = (const float*)d_in[6];
    const float* Wo   = (const float*)d_in[7];
    const float* bo   = (const float*)d_in[8];
    float* ws  = (float*)d_ws;
    ushort* kB = (ushort*)(ws);
    ushort* qB = (ushort*)(ws + 4194304);
    ushort* vB = (ushort*)(ws + 8388608);
    ushort* Xb = (ushort*)(ws + 12582912);
    ushort* Wb = (ushort*)(ws + 16777216);
    float* out = (float*)d_out;

    k_wot <<<1024, 256, 0, stream>>>(Wo, Wb);
    k_proj<<< 512, 256, 0, stream>>>(vals, keys, qrys, Wv, Wk, Wq, kB, qB, vB);
    k_attn<<< 512, 512, 0, stream>>>(kB, qB, vB, mask, Xb);
    k_wo  <<< 512, 512, 0, stream>>>(Xb, Wb, bo, out);
}

// Round 23
// 97.453 us; speedup vs baseline: 9.5551x; 1.0018x over previous
//
#include <hip/hip_runtime.h>

// EntailmentSelfAttention: N=16, L=256, S=2, H=16, D=64, E=1024
//
// Pipeline (4 kernels):
//   K0 k_wot  : Wb[f][e'] = bf16(Wo[f][perm(e')]) (frozen, r17).
//   K1 k_proj : v3 streaming MFMA, 512 thr (8 waves), wave strip 32 l.
//               r22: 56us @ 1.8 TB/s effective on strided 256B-segment
//               reads with only 8 waves/CU (2/SIMD) - not enough loads in
//               flight. Same blocks/bytes, 2x waves -> 2x MLP.
//   K2 k_attn : fused stats+PV MFMA v2 (frozen, r21).
//   K3 k_wo   : bf16 MFMA GEMM (frozen, r17).
//
// ws layout (f32-elem offsets): kB @0, qB @4194304, vB @8388608,
//   Xb @12582912, Wb @16777216.

typedef __attribute__((ext_vector_type(8))) short bf16x8;
typedef __attribute__((ext_vector_type(4))) float f32x4;

__device__ inline ushort f2bf(float x) {
    uint u = __float_as_uint(x);
    u += 0x7FFFu + ((u >> 16) & 1u);
    return (ushort)(u >> 16);
}

__global__ __launch_bounds__(256) void k_wot(
    const float* __restrict__ Wo, ushort* __restrict__ Wb)
{
    const int f = blockIdx.x;          // 0..1023
    const int e4 = threadIdx.x * 4;    // e' base (d%4==0, fixed hr/sp)
    const int hr = e4 >> 7, sp = (e4 >> 6) & 1, d = e4 & 63;
    const float* wrow = Wo + (long)f * 1024 + hr * 128 + 2 * d + sp;
    ushort o[4] = {f2bf(wrow[0]), f2bf(wrow[2]), f2bf(wrow[4]), f2bf(wrow[6])};
    *(uint2*)(Wb + (long)f * 1024 + e4) = *(uint2*)o;
}

// Streaming MFMA projections v3: block = (n,h,s) slice; 512 thr = 8 waves;
// wave owns l-strip [wid*32,+32) (2 l-tiles). A-op = W (LDS), B-op = A rows
// (global direct). D col=l,row=e -> uint2 stores. One barrier total.
__global__ __launch_bounds__(512) void k_proj(
    const float* __restrict__ Av, const float* __restrict__ Ak,
    const float* __restrict__ Aq, const float* __restrict__ Wv,
    const float* __restrict__ Wk, const float* __restrict__ Wq,
    ushort* __restrict__ kB, ushort* __restrict__ qB,
    ushort* __restrict__ vB)
{
    __shared__ ushort Wsb[3][64][72];   // 27,648 B  [m][e][d]
    const int b = blockIdx.x;
    const int n = b >> 5, h = (b >> 1) & 15, s = b & 1;
    const float* Asrc[3] = {Av, Ak, Aq};
    const float* Wsrc[3] = {Wv, Wk, Wq};
    const int tid = threadIdx.x;
    const int wid = tid >> 6, lane = tid & 63;
    const int lr = lane & 15, lk = lane >> 4;

    const long abase = (long)n * 524288 + s * 1024 + h * 64;
    const long slice = ((long)((n * 16 + h) * 2 + s)) * 16384;
    ushort* Bdst[3] = {vB, kB, qB};

    // stage all 3 W matrices once (f32 -> bf16): 1024 chunks/m, 512 thr
#pragma unroll
    for (int m = 0; m < 3; ++m)
#pragma unroll
        for (int w = 0; w < 2; ++w) {
            int idx = w * 512 + tid;
            int r = idx >> 4, c4 = (idx & 15) * 4;
            float4 v = *(const float4*)(Wsrc[m] + r * 64 + c4);
            ushort t4[4] = {f2bf(v.x), f2bf(v.y), f2bf(v.z), f2bf(v.w)};
            *(uint2*)&Wsb[m][r][c4] = *(uint2*)t4;
        }
    __syncthreads();   // the only barrier

    const int l0 = wid * 32;
#pragma unroll 1
    for (int m = 0; m < 3; ++m) {
        const float* A = Asrc[m];
        ushort* B = Bdst[m];
#pragma unroll
        for (int lt = 0; lt < 2; ++lt) {
            const int lrow = l0 + lt * 16 + lr;
            const float* arow = A + abase + (long)lrow * 2048;
            // B-op frags direct from global (col=l -> lane's own row)
            bf16x8 bfrag[2];
#pragma unroll
            for (int ks = 0; ks < 2; ++ks) {
                float4 v0 = *(const float4*)(arow + ks * 32 + lk * 8);
                float4 v1 = *(const float4*)(arow + ks * 32 + lk * 8 + 4);
                ushort t8[8] = {f2bf(v0.x), f2bf(v0.y), f2bf(v0.z), f2bf(v0.w),
                                f2bf(v1.x), f2bf(v1.y), f2bf(v1.z), f2bf(v1.w)};
                bfrag[ks] = *(bf16x8*)t8;
            }
#pragma unroll
            for (int et = 0; et < 4; ++et) {
                f32x4 acc;
#pragma unroll
                for (int rg = 0; rg < 4; ++rg) acc[rg] = 0.f;
#pragma unroll
                for (int ks = 0; ks < 2; ++ks) {
                    bf16x8 wfrag = *(const bf16x8*)
                        &Wsb[m][et * 16 + lr][ks * 32 + lk * 8];
                    acc = __builtin_amdgcn_mfma_f32_16x16x32_bf16(
                        wfrag, bfrag[ks], acc, 0, 0, 0);
                }
                // D: col=l=lrow (lane's lr), row=e=et*16+lk*4+rg
                ushort t4[4] = {f2bf(acc[0]), f2bf(acc[1]),
                                f2bf(acc[2]), f2bf(acc[3])};
                *(uint2*)(B + slice + (long)lrow * 64 + et * 16 + lk * 4) =
                    *(uint2*)t4;
            }
        }
    }
}

// Fused stats+PV v2 (frozen, r21): one block per nhs, 512 thr = 8 waves.
__global__ __launch_bounds__(512) void k_attn(
    const ushort* __restrict__ kB, const ushort* __restrict__ qB,
    const ushort* __restrict__ vB, const int* __restrict__ mask,
    ushort* __restrict__ Xb)
{
    __shared__ ushort Ks[32][72];     //  4,608 B  [l][k]
    __shared__ ushort vsT[64][44];    //  5,632 B  [d][l]
    __shared__ ushort Es[128][44];    // 11,264 B  [wave-q][l]
    __shared__ float Zl[256];         //  1,024 B
    __shared__ int mb16[16];
    const int nhs = blockIdx.x;
    const int n = nhs >> 5, h = (nhs >> 1) & 15, s = nhs & 1;
    const long slice = (long)nhs * 16384;
    const int tid = threadIdx.x;
    const int wid = tid >> 6, lane = tid & 63;
    const int lr = lane & 15, lk = lane >> 4;

    bf16x8 aq[2][2];
#pragma unroll
    for (int qt = 0; qt < 2; ++qt) {
        const int qb = wid * 32 + qt * 16;
        aq[qt][0] = *(const bf16x8*)(qB + slice + (qb + lr) * 64 + lk * 8);
        aq[qt][1] = *(const bf16x8*)(qB + slice + (qb + lr) * 64 + 32 + lk * 8);
    }
    const int mrow = n * 524288 + (h >> 3) * 262144 + (h & 7) * 32 + s * 16;
    if (tid < 16) mb16[tid] = mask[mrow + tid];
    if (tid < 256) Zl[tid] = 0.f;

    const float scale = 0.03125f;

    // ========== PHASE 1: Z accumulation ==========
#pragma unroll 1
    for (int sl = 0; sl < 8; ++sl) {
        __syncthreads();
        if (tid < 256) {
            int r = tid >> 3, c8 = (tid & 7) * 8;
            *(uint4*)&Ks[r][c8] =
                *(const uint4*)(kB + slice + (sl * 32 + r) * 64 + c8);
        }
        __syncthreads();

        float zlt[2] = {0.f, 0.f};
#pragma unroll
        for (int qt = 0; qt < 2; ++qt) {
            const int qb = wid * 32 + qt * 16;
            if (mb16[qb >> 4] == 0) continue;
#pragma unroll
            for (int lt = 0; lt < 2; ++lt) {
                f32x4 sacc;
#pragma unroll
                for (int rg = 0; rg < 4; ++rg) sacc[rg] = 0.f;
                bf16x8 b0 = *(const bf16x8*)&Ks[lt * 16 + lr][lk * 8];
                bf16x8 b1 = *(const bf16x8*)&Ks[lt * 16 + lr][32 + lk * 8];
                sacc = __builtin_amdgcn_mfma_f32_16x16x32_bf16(
                    aq[qt][0], b0, sacc, 0, 0, 0);
                sacc = __builtin_amdgcn_mfma_f32_16x16x32_bf16(
                    aq[qt][1], b1, sacc, 0, 0, 0);
#pragma unroll
                for (int rg = 0; rg < 4; ++rg)
                    zlt[lt] += __expf(sacc[rg] * scale);
            }
        }
#pragma unroll
        for (int lt = 0; lt < 2; ++lt) {
            float v = zlt[lt];
            v += __shfl_xor(v, 16);
            v += __shfl_xor(v, 32);
            if (lk == 0)
                atomicAdd(&Zl[sl * 32 + lt * 16 + lr], v);
        }
    }

    __syncthreads();
    if (tid < 256) {
        float z = Zl[tid];
        Zl[tid] = (z > 0.f) ? 1.0f / z : 1.0f / 256.0f;
    }

    // ========== PHASE 2: att + PV ==========
    f32x4 acc0[4], acc1[4];
#pragma unroll
    for (int dt = 0; dt < 4; ++dt)
#pragma unroll
        for (int rg = 0; rg < 4; ++rg) { acc0[dt][rg] = 0.f; acc1[dt][rg] = 0.f; }

#pragma unroll 1
    for (int sl = 0; sl < 8; ++sl) {
        __syncthreads();
        if (tid < 256) {
            int r = tid >> 3, c8 = (tid & 7) * 8;
            *(uint4*)&Ks[r][c8] =
                *(const uint4*)(kB + slice + (sl * 32 + r) * 64 + c8);
        } else {
            int t = tid - 256;
            int l = t >> 3, d8 = (t & 7) * 8;
            uint4 vv = *(const uint4*)(vB + slice + (sl * 32 + l) * 64 + d8);
            ushort t8[8];
            *(uint4*)t8 = vv;
#pragma unroll
            for (int u = 0; u < 8; ++u) vsT[d8 + u][l] = t8[u];
        }
        __syncthreads();

#pragma unroll
        for (int qt = 0; qt < 2; ++qt) {
            const int qb = wid * 32 + qt * 16;
            const bool live = (mb16[qb >> 4] != 0);
#pragma unroll
            for (int lt = 0; lt < 2; ++lt) {
                f32x4 sacc;
#pragma unroll
                for (int rg = 0; rg < 4; ++rg) sacc[rg] = 0.f;
                bf16x8 b0 = *(const bf16x8*)&Ks[lt * 16 + lr][lk * 8];
                bf16x8 b1 = *(const bf16x8*)&Ks[lt * 16 + lr][32 + lk * 8];
                sacc = __builtin_amdgcn_mfma_f32_16x16x32_bf16(
                    aq[qt][0], b0, sacc, 0, 0, 0);
                sacc = __builtin_amdgcn_mfma_f32_16x16x32_bf16(
                    aq[qt][1], b1, sacc, 0, 0, 0);
                const int l = lt * 16 + lr;
                const float iz = Zl[sl * 32 + l];
#pragma unroll
                for (int rg = 0; rg < 4; ++rg) {
                    float ev = live ? __expf(sacc[rg] * scale) * iz : 0.f;
                    Es[wid * 16 + lk * 4 + rg][l] = f2bf(ev);
                }
            }
            __builtin_amdgcn_s_waitcnt(0);  // lgkmcnt(0): wave-local Es
            bf16x8 aP = *(const bf16x8*)&Es[wid * 16 + lr][lk * 8];
            f32x4* accp = (qt == 0) ? acc0 : acc1;
#pragma unroll
            for (int dt = 0; dt < 4; ++dt) {
                bf16x8 bV = *(const bf16x8*)&vsT[dt * 16 + lr][lk * 8];
                accp[dt] = __builtin_amdgcn_mfma_f32_16x16x32_bf16(
                    aP, bV, accp[dt], 0, 0, 0);
            }
        }
    }

#pragma unroll
    for (int qt = 0; qt < 2; ++qt) {
        const f32x4* accp = (qt == 0) ? acc0 : acc1;
        const int qb = wid * 32 + qt * 16;
#pragma unroll
        for (int dt = 0; dt < 4; ++dt) {
#pragma unroll
            for (int rg = 0; rg < 4; ++rg) {
                const int q = qb + lk * 4 + rg;
                const int d = dt * 16 + lr;
                Xb[slice + (long)q * 64 + d] = f2bf(accp[dt][rg]);
            }
        }
    }
}

// MFMA k_wo (frozen, r17).
__global__ __launch_bounds__(512) void k_wo(
    const ushort* __restrict__ Xb, const ushort* __restrict__ Wb,
    const float* __restrict__ bo, float* __restrict__ out)
{
    __shared__ ushort Xs[128][72];
    __shared__ ushort Ws[128][72];
    const int b = blockIdx.x;
    const int by = b >> 3, bx = b & 7;
    const int r0 = by * 128, f0 = bx * 128;
    const int tid = threadIdx.x;
    const int wid = tid >> 6, lane = tid & 63;
    const int wr = wid >> 2, wc = wid & 3;
    const int lr = lane & 15, lk = lane >> 4;

    f32x4 acc[4][2];
#pragma unroll
    for (int rt = 0; rt < 4; ++rt)
#pragma unroll
        for (int ft = 0; ft < 2; ++ft)
#pragma unroll
            for (int rg = 0; rg < 4; ++rg) acc[rt][ft][rg] = 0.f;

    const int sr = tid >> 2, sc = (tid & 3) * 16;
    const int sR = r0 + sr;
    const int sn = sR >> 9, sq = (sR >> 1) & 255, ss2 = sR & 1;

#pragma unroll 1
    for (int eo = 0; eo < 1024; eo += 64) {
        const int hr = eo >> 7, sp = (eo >> 6) & 1;
        __syncthreads();
        {
            long xo = ((long)((sn * 16 + (ss2 * 8 + hr)) * 2 + sp)) * 16384 +
                      sq * 64 + sc;
            *(uint4*)&Xs[sr][sc] = *(const uint4*)(Xb + xo);
            *(uint4*)&Xs[sr][sc + 8] = *(const uint4*)(Xb + xo + 8);
            long wo = (long)(f0 + sr) * 1024 + eo + sc;
            *(uint4*)&Ws[sr][sc] = *(const uint4*)(Wb + wo);
            *(uint4*)&Ws[sr][sc + 8] = *(const uint4*)(Wb + wo + 8);
        }
        __syncthreads();

#pragma unroll
        for (int ks = 0; ks < 2; ++ks) {
            bf16x8 a[4], bb[2];
#pragma unroll
            for (int rt = 0; rt < 4; ++rt)
                a[rt] = *(const bf16x8*)
                    &Xs[wr * 64 + rt * 16 + lr][ks * 32 + lk * 8];
#pragma unroll
            for (int ft = 0; ft < 2; ++ft)
                bb[ft] = *(const bf16x8*)
                    &Ws[wc * 32 + ft * 16 + lr][ks * 32 + lk * 8];
#pragma unroll
            for (int rt = 0; rt < 4; ++rt)
#pragma unroll
                for (int ft = 0; ft < 2; ++ft)
                    acc[rt][ft] = __builtin_amdgcn_mfma_f32_16x16x32_bf16(
                        a[rt], bb[ft], acc[rt][ft], 0, 0, 0);
        }
    }

#pragma unroll
    for (int ft = 0; ft < 2; ++ft) {
        const int f = f0 + wc * 32 + ft * 16 + lr;
        const float bias = bo[f];
#pragma unroll
        for (int rt = 0; rt < 4; ++rt) {
#pragma unroll
            for (int rg = 0; rg < 4; ++rg) {
                const int r = r0 + wr * 64 + rt * 16 + lk * 4 + rg;
                out[(long)r * 1024 + f] = acc[rt][ft][rg] + bias;
            }
        }
    }
}

extern "C" void kernel_launch(void* const* d_in, const int* in_sizes, int n_in,
                              void* d_out, int out_size, void* d_ws,
                              size_t ws_size, hipStream_t stream)
{
    const float* vals = (const float*)d_in[0];
    const float* keys = (const float*)d_in[1];
    const float* qrys = (const float*)d_in[2];
    const int*   mask = (const int*)d_in[3];
    const float* Wv   = (const float*)d_in[4];
    const float* Wk   = (const float*)d_in[5];
    const float* Wq   = (const float*)d_in[6];
    const float* Wo   = (const float*)d_in[7];
    const float* bo   = (const float*)d_in[8];
    float* ws  = (float*)d_ws;
    ushort* kB = (ushort*)(ws);
    ushort* qB = (ushort*)(ws + 4194304);
    ushort* vB = (ushort*)(ws + 8388608);
    ushort* Xb = (ushort*)(ws + 12582912);
    ushort* Wb = (ushort*)(ws + 16777216);
    float* out = (float*)d_out;

    k_wot <<<1024, 256, 0, stream>>>(Wo, Wb);
    k_proj<<< 512, 512, 0, stream>>>(vals, keys, qrys, Wv, Wk, Wq, kB, qB, vB);
    k_attn<<< 512, 512, 0, stream>>>(kB, qB, vB, mask, Xb);
    k_wo  <<< 512, 512, 0, stream>>>(Xb, Wb, bo, out);
}